// Round 1
// baseline (777.329 us; speedup 1.0000x reference)
//
#include <hip/hip_runtime.h>
#include <math.h>

#define BB 128
#define QQ 900
#define GG 80
#define CC 92
#define NCL 91

// ---------------- ws layout (bytes) ----------------
// cost  : float[BB*GG*QQ]      @ 0           (36,864,000)
// lse   : float[BB*QQ]         @ 36,864,000  (460,800)
// vidx  : int[BB*GG]           @ 37,324,800  (40,960)
// nval  : int[BB]              @ 37,365,760  (512)
// mq    : int[BB*GG]           @ 37,366,272  (40,960)
// acc   : double[4]            @ 37,407,232  (32)   [S_base, ce_adj, l1, giou]
#define COST_OFF 0
#define LSE_OFF  36864000
#define VIDX_OFF 37324800
#define NV_OFF   37365760
#define MQ_OFF   37366272
#define ACC_OFF  37407232

// Per-batch compaction of valid gt indices (label < 91).
__global__ void compact_kernel(const int* __restrict__ glabels, int* __restrict__ valid_idx,
                               int* __restrict__ nvalid) {
    int b = blockIdx.x * blockDim.x + threadIdx.x;
    if (b >= BB) return;
    int cnt = 0;
    for (int g = 0; g < GG; ++g)
        if (glabels[b * GG + g] < NCL) valid_idx[b * GG + (cnt++)] = g;
    nvalid[b] = cnt;
}

// One wave per (b,q) row: lse = max + log(sum(exp(x - max))) over 92 classes.
__global__ void lse_kernel(const float* __restrict__ logits, float* __restrict__ lse) {
    int wid = (blockIdx.x * blockDim.x + threadIdx.x) >> 6;
    int lane = threadIdx.x & 63;
    if (wid >= BB * QQ) return;
    const float* row = logits + (size_t)wid * CC;
    float e0 = row[lane];
    float e1 = (lane + 64 < CC) ? row[lane + 64] : -INFINITY;
    float mx = fmaxf(e0, e1);
#pragma unroll
    for (int off = 32; off; off >>= 1) mx = fmaxf(mx, __shfl_down(mx, off));
    mx = __shfl(mx, 0);
    float s = expf(e0 - mx) + ((lane + 64 < CC) ? expf(e1 - mx) : 0.f);
#pragma unroll
    for (int off = 32; off; off >>= 1) s += __shfl_down(s, off);
    if (lane == 0) lse[wid] = mx + logf(s);
}

// cost_T[b][k][q] for compacted valid row k (gt index g): 5*L1 + class - 2*giou.
__global__ void cost_kernel(const float* __restrict__ logits, const float* __restrict__ pboxes,
                            const float* __restrict__ gboxes, const int* __restrict__ glabels,
                            const float* __restrict__ lse, const int* __restrict__ valid_idx,
                            const int* __restrict__ nvalid, float* __restrict__ cost) {
    int b = blockIdx.x / GG, k = blockIdx.x % GG;
    if (k >= nvalid[b]) return;
    int g = valid_idx[b * GG + k];
    int label = glabels[b * GG + g];  // < 91 guaranteed (valid)
    float4 gb = ((const float4*)gboxes)[b * GG + g];
    float gx0 = gb.x - 0.5f * gb.z, gy0 = gb.y - 0.5f * gb.w;
    float gx1 = gb.x + 0.5f * gb.z, gy1 = gb.y + 0.5f * gb.w;
    float garea = (gx1 - gx0) * (gy1 - gy0);
    float* crow = cost + ((size_t)(b * GG + k)) * QQ;
    for (int q = threadIdx.x; q < QQ; q += blockDim.x) {
        float4 pb = ((const float4*)pboxes)[b * QQ + q];
        float l1 = fabsf(pb.x - gb.x) + fabsf(pb.y - gb.y) + fabsf(pb.z - gb.z) + fabsf(pb.w - gb.w);
        float px0 = pb.x - 0.5f * pb.z, py0 = pb.y - 0.5f * pb.w;
        float px1 = pb.x + 0.5f * pb.z, py1 = pb.y + 0.5f * pb.w;
        float parea = (px1 - px0) * (py1 - py0);
        float ltx = fmaxf(px0, gx0), lty = fmaxf(py0, gy0);
        float rbx = fminf(px1, gx1), rby = fminf(py1, gy1);
        float iw = fmaxf(rbx - ltx, 0.f), ih = fmaxf(rby - lty, 0.f);
        float inter = iw * ih;
        float uni = parea + garea - inter;
        float iou = inter / uni;
        float cx0 = fminf(px0, gx0), cy0 = fminf(py0, gy0);
        float cx1 = fmaxf(px1, gx1), cy1 = fmaxf(py1, gy1);
        float cw = fmaxf(cx1 - cx0, 0.f), ch = fmaxf(cy1 - cy0, 0.f);
        float ac = cw * ch;
        float giou = iou - (ac - uni) / ac;
        float cls = lse[b * QQ + q] - logits[((size_t)(b * QQ) + q) * CC + label];
        crow[q] = 5.f * l1 + cls - 2.f * giou;
    }
}

// Rectangular LSA, scipy shortest-augmenting-path semantics, one 64-lane wave per batch.
// Rows = compacted valid gts (n <= 80), cols = queries (m = 900). fp64 duals.
__global__ __launch_bounds__(64) void lsa_kernel(const float* __restrict__ cost,
                                                 const int* __restrict__ nvalid,
                                                 int* __restrict__ match_q) {
    __shared__ double v_s[QQ];
    __shared__ double short_s[QQ];
    __shared__ int path_s[QQ];
    __shared__ int row4col_s[QQ];
    __shared__ unsigned char SC_s[QQ];
    __shared__ double u_s[GG];
    __shared__ unsigned char SR_s[GG];
    __shared__ int col4row_s[GG];

    int b = blockIdx.x;
    int lane = threadIdx.x;
    int n = nvalid[b];
    const float* cbase = cost + (size_t)b * GG * QQ;

    for (int j = lane; j < QQ; j += 64) { v_s[j] = 0.0; row4col_s[j] = -1; }
    for (int i = lane; i < GG; i += 64) { u_s[i] = 0.0; col4row_s[i] = -1; }
    __syncthreads();

    for (int cur = 0; cur < n; ++cur) {
        for (int j = lane; j < QQ; j += 64) { short_s[j] = INFINITY; SC_s[j] = 0; }
        for (int i = lane; i < GG; i += 64) SR_s[i] = 0;
        if (lane == 0) SR_s[cur] = 1;
        __syncthreads();

        int i = cur;
        double minv = 0.0;
        int sink = -1;
        for (int it = 0; it < QQ && sink == -1; ++it) {
            double ui = u_s[i];
            const float* crow = cbase + (size_t)i * QQ;
            double lmin = INFINITY;
            int lj = QQ;  // sentinel > any real column (tie-break = lowest index)
            for (int j = lane; j < QQ; j += 64) {
                if (!SC_s[j]) {
                    double r = minv + (double)crow[j] - ui - v_s[j];
                    if (r < short_s[j]) { short_s[j] = r; path_s[j] = i; }
                    double sj = short_s[j];
                    if (sj < lmin || (sj == lmin && j < lj)) { lmin = sj; lj = j; }
                }
            }
#pragma unroll
            for (int off = 32; off; off >>= 1) {
                double ov = __shfl_down(lmin, off);
                int oj = __shfl_down(lj, off);
                if (ov < lmin || (ov == lmin && oj < lj)) { lmin = ov; lj = oj; }
            }
            lmin = __shfl(lmin, 0);
            lj = __shfl(lj, 0);
            minv = lmin;
            int r4c = row4col_s[lj];
            __syncthreads();
            if (lane == 0) SC_s[lj] = 1;
            if (r4c == -1) {
                sink = lj;
            } else {
                i = r4c;
                if (lane == 0) SR_s[i] = 1;
            }
            __syncthreads();
        }
        // dual updates (before augmentation, matching reference order)
        if (lane == 0) u_s[cur] += minv;
        for (int ii = lane; ii < n; ii += 64)
            if (SR_s[ii] && ii != cur) u_s[ii] += minv - short_s[col4row_s[ii]];
        for (int j = lane; j < QQ; j += 64)
            if (SC_s[j]) v_s[j] -= minv - short_s[j];
        __syncthreads();
        // augment
        if (lane == 0) {
            int j = sink;
            while (true) {
                int pi = path_s[j];
                row4col_s[j] = pi;
                int nj = col4row_s[pi];
                col4row_s[pi] = j;
                j = nj;
                if (pi == cur) break;
            }
        }
        __syncthreads();
    }
    for (int i = lane; i < n; i += 64) match_q[b * GG + i] = col4row_s[i];
}

// Base CE sum: all (b,q) treated as no-object (class 91, weight 1.0).
__global__ void ce_base_kernel(const float* __restrict__ logits, const float* __restrict__ lse,
                               double* __restrict__ acc) {
    __shared__ double sd[256];
    int idx = blockIdx.x * 256 + threadIdx.x;
    double v = 0.0;
    if (idx < BB * QQ) v = (double)lse[idx] - (double)logits[(size_t)idx * CC + NCL];
    sd[threadIdx.x] = v;
    __syncthreads();
    for (int s = 128; s; s >>= 1) {
        if (threadIdx.x < s) sd[threadIdx.x] += sd[threadIdx.x + s];
        __syncthreads();
    }
    if (threadIdx.x == 0) atomicAdd(&acc[0], sd[0]);
}

// Per matched pair: CE adjustment, L1 sum, (1 - giou) sum.
__global__ void matched_kernel(const float* __restrict__ logits, const float* __restrict__ pboxes,
                               const float* __restrict__ gboxes, const int* __restrict__ glabels,
                               const float* __restrict__ lse, const int* __restrict__ valid_idx,
                               const int* __restrict__ nvalid, const int* __restrict__ match_q,
                               double* __restrict__ acc) {
    int t = blockIdx.x * blockDim.x + threadIdx.x;
    if (t >= BB * GG) return;
    int b = t / GG, k = t % GG;
    if (k >= nvalid[b]) return;
    int g = valid_idx[b * GG + k];
    int q = match_q[b * GG + k];
    int label = glabels[b * GG + g];
    size_t ro = ((size_t)b * QQ + q) * CC;
    float ls = lse[b * QQ + q];
    float nll_lab = ls - logits[ro + label];
    float nll_no = ls - logits[ro + NCL];
    double ce_adj = 0.1 * (double)nll_lab - (double)nll_no;

    float4 pb = ((const float4*)pboxes)[b * QQ + q];
    float4 gb = ((const float4*)gboxes)[b * GG + g];
    float l1 = fabsf(pb.x - gb.x) + fabsf(pb.y - gb.y) + fabsf(pb.z - gb.z) + fabsf(pb.w - gb.w);

    float px0 = pb.x - 0.5f * pb.z, py0 = pb.y - 0.5f * pb.w;
    float px1 = pb.x + 0.5f * pb.z, py1 = pb.y + 0.5f * pb.w;
    float gx0 = gb.x - 0.5f * gb.z, gy0 = gb.y - 0.5f * gb.w;
    float gx1 = gb.x + 0.5f * gb.z, gy1 = gb.y + 0.5f * gb.w;
    float parea = (px1 - px0) * (py1 - py0);
    float garea = (gx1 - gx0) * (gy1 - gy0);
    float ltx = fmaxf(px0, gx0), lty = fmaxf(py0, gy0);
    float rbx = fminf(px1, gx1), rby = fminf(py1, gy1);
    float iw = fmaxf(rbx - ltx, 0.f), ih = fmaxf(rby - lty, 0.f);
    float inter = iw * ih;
    float uni = parea + garea - inter;
    float iou = inter / uni;
    float cx0 = fminf(px0, gx0), cy0 = fminf(py0, gy0);
    float cx1 = fmaxf(px1, gx1), cy1 = fmaxf(py1, gy1);
    float cw = fmaxf(cx1 - cx0, 0.f), ch = fmaxf(cy1 - cy0, 0.f);
    float ac = cw * ch;
    float giou = iou - (ac - uni) / ac;

    atomicAdd(&acc[1], ce_adj);
    atomicAdd(&acc[2], (double)l1);
    atomicAdd(&acc[3], 1.0 - (double)giou);
}

__global__ void final_kernel(const int* __restrict__ nvalid, const double* __restrict__ acc,
                             float* __restrict__ out) {
    if (blockIdx.x == 0 && threadIdx.x == 0) {
        int M = 0;
        for (int b = 0; b < BB; ++b) M += nvalid[b];
        double sum_w = (double)(BB * QQ) - 0.9 * (double)M;
        out[0] = (float)((acc[0] + acc[1]) / sum_w);
        out[1] = (float)(acc[2] / (4.0 * (double)M));
        out[2] = (float)(acc[3] / (double)M);
    }
}

extern "C" void kernel_launch(void* const* d_in, const int* in_sizes, int n_in,
                              void* d_out, int out_size, void* d_ws, size_t ws_size,
                              hipStream_t stream) {
    const float* logits = (const float*)d_in[0];   // [B,Q,92]
    const float* pboxes = (const float*)d_in[1];   // [B,Q,4]
    const int* glabels = (const int*)d_in[2];      // [B,G]
    const float* gboxes = (const float*)d_in[3];   // [B,G,4]
    float* out = (float*)d_out;

    char* ws = (char*)d_ws;
    float* cost = (float*)(ws + COST_OFF);
    float* lse = (float*)(ws + LSE_OFF);
    int* vidx = (int*)(ws + VIDX_OFF);
    int* nval = (int*)(ws + NV_OFF);
    int* mq = (int*)(ws + MQ_OFF);
    double* acc = (double*)(ws + ACC_OFF);

    hipMemsetAsync(acc, 0, 4 * sizeof(double), stream);
    compact_kernel<<<1, 128, 0, stream>>>(glabels, vidx, nval);
    lse_kernel<<<(BB * QQ * 64) / 256, 256, 0, stream>>>(logits, lse);
    cost_kernel<<<BB * GG, 256, 0, stream>>>(logits, pboxes, gboxes, glabels, lse, vidx, nval, cost);
    lsa_kernel<<<BB, 64, 0, stream>>>(cost, nval, mq);
    ce_base_kernel<<<450, 256, 0, stream>>>(logits, lse, acc);
    matched_kernel<<<(BB * GG + 255) / 256, 256, 0, stream>>>(logits, pboxes, gboxes, glabels, lse,
                                                              vidx, nval, mq, acc);
    final_kernel<<<1, 1, 0, stream>>>(nval, acc, out);
}

// Round 2
// 618.216 us; speedup vs baseline: 1.2574x; 1.2574x over previous
//
#include <hip/hip_runtime.h>
#include <math.h>

#define BB 128
#define QQ 900
#define GG 80
#define CC 92
#define NCL 91
#define NSLOT 15  // ceil(QQ/64)

// ---------------- ws layout (bytes) ----------------
#define COST_OFF 0            // float[BB*GG*QQ]  36,864,000
#define LSE_OFF  36864000     // float[BB*QQ]
#define VIDX_OFF 37324800     // int[BB*GG]
#define NV_OFF   37365760     // int[BB]
#define MQ_OFF   37366272     // int[BB*GG]
#define ACC_OFF  37407232     // double[4]  [S_base, ce_adj, l1, giou]

// Per-batch compaction of valid gt indices (label < 91).
__global__ void compact_kernel(const int* __restrict__ glabels, int* __restrict__ valid_idx,
                               int* __restrict__ nvalid) {
    int b = blockIdx.x * blockDim.x + threadIdx.x;
    if (b >= BB) return;
    int cnt = 0;
    for (int g = 0; g < GG; ++g)
        if (glabels[b * GG + g] < NCL) valid_idx[b * GG + (cnt++)] = g;
    nvalid[b] = cnt;
}

// Grid-stride: one wave per (b,q) row. Computes lse AND accumulates the
// no-object CE base sum  sum(lse - logit[91])  (fused former ce_base_kernel).
__global__ void lse_kernel(const float* __restrict__ logits, float* __restrict__ lse,
                           double* __restrict__ acc) {
    __shared__ double sd[4];
    int lane = threadIdx.x & 63;
    int wslot = threadIdx.x >> 6;
    int gwave = (blockIdx.x * blockDim.x + threadIdx.x) >> 6;
    int nwaves = (gridDim.x * blockDim.x) >> 6;
    double local = 0.0;
    for (int wid = gwave; wid < BB * QQ; wid += nwaves) {
        const float* row = logits + (size_t)wid * CC;
        float e0 = row[lane];
        float e1 = (lane < CC - 64) ? row[lane + 64] : -INFINITY;
        float mx = fmaxf(e0, e1);
#pragma unroll
        for (int off = 32; off; off >>= 1) mx = fmaxf(mx, __shfl_down(mx, off));
        mx = __shfl(mx, 0);
        float s = expf(e0 - mx) + ((lane < CC - 64) ? expf(e1 - mx) : 0.f);
#pragma unroll
        for (int off = 32; off; off >>= 1) s += __shfl_down(s, off);
        s = __shfl(s, 0);
        float l = mx + logf(s);
        float no = __shfl(e1, NCL - 64);  // lane 27 holds row[91]
        if (lane == 0) {
            lse[wid] = l;
            local += (double)l - (double)no;
        }
    }
    if (lane == 0) sd[wslot] = local;
    __syncthreads();
    if (threadIdx.x == 0) {
        double t = 0.0;
        for (int w = 0; w < 4; ++w) t += sd[w];
        atomicAdd(&acc[0], t);
    }
}

// cost_T[b][k][q] for compacted valid row k (gt index g): 5*L1 + class - 2*giou.
__global__ void cost_kernel(const float* __restrict__ logits, const float* __restrict__ pboxes,
                            const float* __restrict__ gboxes, const int* __restrict__ glabels,
                            const float* __restrict__ lse, const int* __restrict__ valid_idx,
                            const int* __restrict__ nvalid, float* __restrict__ cost) {
    int b = blockIdx.x / GG, k = blockIdx.x % GG;
    if (k >= nvalid[b]) return;
    int g = valid_idx[b * GG + k];
    int label = glabels[b * GG + g];
    float4 gb = ((const float4*)gboxes)[b * GG + g];
    float gx0 = gb.x - 0.5f * gb.z, gy0 = gb.y - 0.5f * gb.w;
    float gx1 = gb.x + 0.5f * gb.z, gy1 = gb.y + 0.5f * gb.w;
    float garea = (gx1 - gx0) * (gy1 - gy0);
    float* crow = cost + ((size_t)(b * GG + k)) * QQ;
    for (int q = threadIdx.x; q < QQ; q += blockDim.x) {
        float4 pb = ((const float4*)pboxes)[b * QQ + q];
        float l1 = fabsf(pb.x - gb.x) + fabsf(pb.y - gb.y) + fabsf(pb.z - gb.z) + fabsf(pb.w - gb.w);
        float px0 = pb.x - 0.5f * pb.z, py0 = pb.y - 0.5f * pb.w;
        float px1 = pb.x + 0.5f * pb.z, py1 = pb.y + 0.5f * pb.w;
        float parea = (px1 - px0) * (py1 - py0);
        float ltx = fmaxf(px0, gx0), lty = fmaxf(py0, gy0);
        float rbx = fminf(px1, gx1), rby = fminf(py1, gy1);
        float iw = fmaxf(rbx - ltx, 0.f), ih = fmaxf(rby - lty, 0.f);
        float inter = iw * ih;
        float uni = parea + garea - inter;
        float iou = inter / uni;
        float cx0 = fminf(px0, gx0), cy0 = fminf(py0, gy0);
        float cx1 = fmaxf(px1, gx1), cy1 = fmaxf(py1, gy1);
        float cw = fmaxf(cx1 - cx0, 0.f), ch = fmaxf(cy1 - cy0, 0.f);
        float ac = cw * ch;
        float giou = iou - (ac - uni) / ac;
        float cls = lse[b * QQ + q] - logits[((size_t)(b * QQ) + q) * CC + label];
        crow[q] = 5.f * l1 + cls - 2.f * giou;
    }
}

// Rectangular LSA, scipy shortest-augmenting-path semantics, one 64-lane wave
// per batch. Per-column state (shortest, v, SC) lives in REGISTERS: lane L
// owns columns j = L, L+64, ..., (15 slots). fp64 duals = exact ref match.
// u[SR] update uses the pop-time log trick: shortest[col4row[r]] == lmin at
// the step row r entered SR (SC'd columns never change afterwards).
__global__ __launch_bounds__(64) void lsa_kernel(const float* __restrict__ cost,
                                                 const int* __restrict__ nvalid,
                                                 int* __restrict__ match_q) {
    __shared__ int path_s[QQ];
    __shared__ int row4col_s[QQ];
    __shared__ int col4row_s[GG];
    __shared__ double u_s[GG];
    __shared__ double srval_s[GG];
    __shared__ unsigned char SR_s[GG];

    int b = blockIdx.x;
    int lane = threadIdx.x;
    int n = nvalid[b];
    const float* cbase = cost + (size_t)b * GG * QQ;

    double v[NSLOT], sh[NSLOT];
    unsigned valid_mask = 0;
#pragma unroll
    for (int s = 0; s < NSLOT; ++s) {
        v[s] = 0.0;
        if (s * 64 + lane < QQ) valid_mask |= (1u << s);
    }
    for (int j = lane; j < QQ; j += 64) row4col_s[j] = -1;
    for (int i = lane; i < GG; i += 64) { col4row_s[i] = -1; u_s[i] = 0.0; }
    __syncthreads();

    for (int cur = 0; cur < n; ++cur) {
        unsigned sc = 0;
#pragma unroll
        for (int s = 0; s < NSLOT; ++s) sh[s] = INFINITY;
        for (int i = lane; i < GG; i += 64) SR_s[i] = 0;
        __syncthreads();

        int i = cur;
        double minv = 0.0;
        int sink = -1;
        while (sink < 0) {
            double ui = u_s[i];  // broadcast LDS read
            const float* crow = cbase + (size_t)i * QQ;
            float cv[NSLOT];
#pragma unroll
            for (int s = 0; s < NSLOT; ++s) {
                int j = s * 64 + lane;
                cv[s] = (j < QQ) ? crow[j] : 0.f;  // independent loads, pipelined
            }
            double lmin = INFINITY;
            int lj = QQ;  // sentinel (tie-break = lowest column index)
#pragma unroll
            for (int s = 0; s < NSLOT; ++s) {
                int j = s * 64 + lane;
                bool active = ((valid_mask >> s) & 1u) && !((sc >> s) & 1u);
                if (active) {
                    double r = minv + (double)cv[s] - ui - v[s];
                    if (r < sh[s]) { sh[s] = r; path_s[j] = i; }
                    if (sh[s] < lmin) { lmin = sh[s]; lj = j; }  // strict < keeps lowest s
                }
            }
#pragma unroll
            for (int off = 32; off; off >>= 1) {
                double ov = __shfl_down(lmin, off);
                int oj = __shfl_down(lj, off);
                if (ov < lmin || (ov == lmin && oj < lj)) { lmin = ov; lj = oj; }
            }
            lmin = __shfl(lmin, 0);
            lj = __shfl(lj, 0);
            minv = lmin;
            if (lane == (lj & 63)) sc |= (1u << (lj >> 6));  // mark SC on owner lane
            int r4c = row4col_s[lj];  // broadcast LDS read
            if (r4c == -1) {
                sink = lj;
            } else {
                i = r4c;
                if (lane == 0) { SR_s[i] = 1; srval_s[i] = lmin; }
            }
        }
        // dual updates (reference order: before augmentation)
        __syncthreads();
        if (lane == 0) u_s[cur] += minv;
        for (int ii = lane; ii < n; ii += 64)
            if (SR_s[ii]) u_s[ii] += minv - srval_s[ii];
#pragma unroll
        for (int s = 0; s < NSLOT; ++s)
            if ((sc >> s) & 1u) v[s] -= (minv - sh[s]);
        // augment
        if (lane == 0) {
            int j = sink;
            while (true) {
                int pi = path_s[j];
                row4col_s[j] = pi;
                int nj = col4row_s[pi];
                col4row_s[pi] = j;
                j = nj;
                if (pi == cur) break;
            }
        }
        __syncthreads();
    }
    for (int i2 = lane; i2 < n; i2 += 64) match_q[b * GG + i2] = col4row_s[i2];
}

// Per matched pair: CE adjustment, L1 sum, (1 - giou) sum.
__global__ void matched_kernel(const float* __restrict__ logits, const float* __restrict__ pboxes,
                               const float* __restrict__ gboxes, const int* __restrict__ glabels,
                               const float* __restrict__ lse, const int* __restrict__ valid_idx,
                               const int* __restrict__ nvalid, const int* __restrict__ match_q,
                               double* __restrict__ acc) {
    int t = blockIdx.x * blockDim.x + threadIdx.x;
    if (t >= BB * GG) return;
    int b = t / GG, k = t % GG;
    if (k >= nvalid[b]) return;
    int g = valid_idx[b * GG + k];
    int q = match_q[b * GG + k];
    int label = glabels[b * GG + g];
    size_t ro = ((size_t)b * QQ + q) * CC;
    float ls = lse[b * QQ + q];
    float nll_lab = ls - logits[ro + label];
    float nll_no = ls - logits[ro + NCL];
    double ce_adj = 0.1 * (double)nll_lab - (double)nll_no;

    float4 pb = ((const float4*)pboxes)[b * QQ + q];
    float4 gb = ((const float4*)gboxes)[b * GG + g];
    float l1 = fabsf(pb.x - gb.x) + fabsf(pb.y - gb.y) + fabsf(pb.z - gb.z) + fabsf(pb.w - gb.w);

    float px0 = pb.x - 0.5f * pb.z, py0 = pb.y - 0.5f * pb.w;
    float px1 = pb.x + 0.5f * pb.z, py1 = pb.y + 0.5f * pb.w;
    float gx0 = gb.x - 0.5f * gb.z, gy0 = gb.y - 0.5f * gb.w;
    float gx1 = gb.x + 0.5f * gb.z, gy1 = gb.y + 0.5f * gb.w;
    float parea = (px1 - px0) * (py1 - py0);
    float garea = (gx1 - gx0) * (gy1 - gy0);
    float ltx = fmaxf(px0, gx0), lty = fmaxf(py0, gy0);
    float rbx = fminf(px1, gx1), rby = fminf(py1, gy1);
    float iw = fmaxf(rbx - ltx, 0.f), ih = fmaxf(rby - lty, 0.f);
    float inter = iw * ih;
    float uni = parea + garea - inter;
    float iou = inter / uni;
    float cx0 = fminf(px0, gx0), cy0 = fminf(py0, gy0);
    float cx1 = fmaxf(px1, gx1), cy1 = fmaxf(py1, gy1);
    float cw = fmaxf(cx1 - cx0, 0.f), ch = fmaxf(cy1 - cy0, 0.f);
    float ac = cw * ch;
    float giou = iou - (ac - uni) / ac;

    atomicAdd(&acc[1], ce_adj);
    atomicAdd(&acc[2], (double)l1);
    atomicAdd(&acc[3], 1.0 - (double)giou);
}

__global__ void final_kernel(const int* __restrict__ nvalid, const double* __restrict__ acc,
                             float* __restrict__ out) {
    if (blockIdx.x == 0 && threadIdx.x == 0) {
        int M = 0;
        for (int b = 0; b < BB; ++b) M += nvalid[b];
        double sum_w = (double)(BB * QQ) - 0.9 * (double)M;
        out[0] = (float)((acc[0] + acc[1]) / sum_w);
        out[1] = (float)(acc[2] / (4.0 * (double)M));
        out[2] = (float)(acc[3] / (double)M);
    }
}

extern "C" void kernel_launch(void* const* d_in, const int* in_sizes, int n_in,
                              void* d_out, int out_size, void* d_ws, size_t ws_size,
                              hipStream_t stream) {
    const float* logits = (const float*)d_in[0];
    const float* pboxes = (const float*)d_in[1];
    const int* glabels = (const int*)d_in[2];
    const float* gboxes = (const float*)d_in[3];
    float* out = (float*)d_out;

    char* ws = (char*)d_ws;
    float* cost = (float*)(ws + COST_OFF);
    float* lse = (float*)(ws + LSE_OFF);
    int* vidx = (int*)(ws + VIDX_OFF);
    int* nval = (int*)(ws + NV_OFF);
    int* mq = (int*)(ws + MQ_OFF);
    double* acc = (double*)(ws + ACC_OFF);

    hipMemsetAsync(acc, 0, 4 * sizeof(double), stream);
    compact_kernel<<<1, 128, 0, stream>>>(glabels, vidx, nval);
    lse_kernel<<<1024, 256, 0, stream>>>(logits, lse, acc);
    cost_kernel<<<BB * GG, 256, 0, stream>>>(logits, pboxes, gboxes, glabels, lse, vidx, nval, cost);
    lsa_kernel<<<BB, 64, 0, stream>>>(cost, nval, mq);
    matched_kernel<<<(BB * GG + 255) / 256, 256, 0, stream>>>(logits, pboxes, gboxes, glabels, lse,
                                                              vidx, nval, mq, acc);
    final_kernel<<<1, 1, 0, stream>>>(nval, acc, out);
}

// Round 3
// 327.944 us; speedup vs baseline: 2.3703x; 1.8851x over previous
//
#include <hip/hip_runtime.h>
#include <math.h>

#define BB 128
#define QQ 900
#define GG 80
#define CC 92
#define NCL 91
#define NSLOT 15  // ceil(QQ/64)

// ---------------- ws layout (bytes) ----------------
#define COST_OFF 0            // float[BB*GG*QQ]  36,864,000
#define LSE_OFF  36864000     // float[BB*QQ]
#define VIDX_OFF 37324800     // int[BB*GG]
#define NV_OFF   37365760     // int[BB]
#define MQ_OFF   37366272     // int[BB*GG]
#define ACC_OFF  37407232     // double[4]  [S_base, ce_adj, l1, giou]

// Per-batch compaction of valid gt indices (label < 91).
__global__ void compact_kernel(const int* __restrict__ glabels, int* __restrict__ valid_idx,
                               int* __restrict__ nvalid) {
    int b = blockIdx.x * blockDim.x + threadIdx.x;
    if (b >= BB) return;
    int cnt = 0;
    for (int g = 0; g < GG; ++g)
        if (glabels[b * GG + g] < NCL) valid_idx[b * GG + (cnt++)] = g;
    nvalid[b] = cnt;
}

// Grid-stride: one wave per (b,q) row. Computes lse AND accumulates the
// no-object CE base sum  sum(lse - logit[91]).
__global__ void lse_kernel(const float* __restrict__ logits, float* __restrict__ lse,
                           double* __restrict__ acc) {
    __shared__ double sd[4];
    int lane = threadIdx.x & 63;
    int wslot = threadIdx.x >> 6;
    int gwave = (blockIdx.x * blockDim.x + threadIdx.x) >> 6;
    int nwaves = (gridDim.x * blockDim.x) >> 6;
    double local = 0.0;
    for (int wid = gwave; wid < BB * QQ; wid += nwaves) {
        const float* row = logits + (size_t)wid * CC;
        float e0 = row[lane];
        float e1 = (lane < CC - 64) ? row[lane + 64] : -INFINITY;
        float mx = fmaxf(e0, e1);
#pragma unroll
        for (int off = 32; off; off >>= 1) mx = fmaxf(mx, __shfl_down(mx, off));
        mx = __shfl(mx, 0);
        float s = expf(e0 - mx) + ((lane < CC - 64) ? expf(e1 - mx) : 0.f);
#pragma unroll
        for (int off = 32; off; off >>= 1) s += __shfl_down(s, off);
        s = __shfl(s, 0);
        float l = mx + logf(s);
        float no = __shfl(e1, NCL - 64);  // lane 27 holds row[91]
        if (lane == 0) {
            lse[wid] = l;
            local += (double)l - (double)no;
        }
    }
    if (lane == 0) sd[wslot] = local;
    __syncthreads();
    if (threadIdx.x == 0) {
        double t = 0.0;
        for (int w = 0; w < 4; ++w) t += sd[w];
        atomicAdd(&acc[0], t);
    }
}

// cost_T[b][k][q] for compacted valid row k (gt index g): 5*L1 + class - 2*giou.
__global__ void cost_kernel(const float* __restrict__ logits, const float* __restrict__ pboxes,
                            const float* __restrict__ gboxes, const int* __restrict__ glabels,
                            const float* __restrict__ lse, const int* __restrict__ valid_idx,
                            const int* __restrict__ nvalid, float* __restrict__ cost) {
    int b = blockIdx.x / GG, k = blockIdx.x % GG;
    if (k >= nvalid[b]) return;
    int g = valid_idx[b * GG + k];
    int label = glabels[b * GG + g];
    float4 gb = ((const float4*)gboxes)[b * GG + g];
    float gx0 = gb.x - 0.5f * gb.z, gy0 = gb.y - 0.5f * gb.w;
    float gx1 = gb.x + 0.5f * gb.z, gy1 = gb.y + 0.5f * gb.w;
    float garea = (gx1 - gx0) * (gy1 - gy0);
    float* crow = cost + ((size_t)(b * GG + k)) * QQ;
    for (int q = threadIdx.x; q < QQ; q += blockDim.x) {
        float4 pb = ((const float4*)pboxes)[b * QQ + q];
        float l1 = fabsf(pb.x - gb.x) + fabsf(pb.y - gb.y) + fabsf(pb.z - gb.z) + fabsf(pb.w - gb.w);
        float px0 = pb.x - 0.5f * pb.z, py0 = pb.y - 0.5f * pb.w;
        float px1 = pb.x + 0.5f * pb.z, py1 = pb.y + 0.5f * pb.w;
        float parea = (px1 - px0) * (py1 - py0);
        float ltx = fmaxf(px0, gx0), lty = fmaxf(py0, gy0);
        float rbx = fminf(px1, gx1), rby = fminf(py1, gy1);
        float iw = fmaxf(rbx - ltx, 0.f), ih = fmaxf(rby - lty, 0.f);
        float inter = iw * ih;
        float uni = parea + garea - inter;
        float iou = inter / uni;
        float cx0 = fminf(px0, gx0), cy0 = fminf(py0, gy0);
        float cx1 = fmaxf(px1, gx1), cy1 = fmaxf(py1, gy1);
        float cw = fmaxf(cx1 - cx0, 0.f), ch = fmaxf(cy1 - cy0, 0.f);
        float ac = cw * ch;
        float giou = iou - (ac - uni) / ac;
        float cls = lse[b * QQ + q] - logits[((size_t)(b * QQ) + q) * CC + label];
        crow[q] = 5.f * l1 + cls - 2.f * giou;
    }
}

// Monotone float<->u32 key map (unsigned compare == float compare).
__device__ __forceinline__ unsigned f2key(float f) {
    unsigned b = __float_as_uint(f);
    return b ^ (unsigned)(((int)b >> 31) | (int)0x80000000);
}
__device__ __forceinline__ float key2f(unsigned k) {
    unsigned b = (k & 0x80000000u) ? (k ^ 0x80000000u) : ~k;
    return __uint_as_float(b);
}

// Wave64 min-reduce via DPP; returns uniform min (readlane 63).
__device__ __forceinline__ unsigned wave_min_u32(unsigned x) {
    unsigned t;
    t = (unsigned)__builtin_amdgcn_update_dpp((int)x, (int)x, 0x111, 0xF, 0xF, false); x = x < t ? x : t;
    t = (unsigned)__builtin_amdgcn_update_dpp((int)x, (int)x, 0x112, 0xF, 0xF, false); x = x < t ? x : t;
    t = (unsigned)__builtin_amdgcn_update_dpp((int)x, (int)x, 0x114, 0xF, 0xF, false); x = x < t ? x : t;
    t = (unsigned)__builtin_amdgcn_update_dpp((int)x, (int)x, 0x118, 0xF, 0xF, false); x = x < t ? x : t;
    t = (unsigned)__builtin_amdgcn_update_dpp((int)x, (int)x, 0x142, 0xF, 0xF, false); x = x < t ? x : t;
    t = (unsigned)__builtin_amdgcn_update_dpp((int)x, (int)x, 0x143, 0xF, 0xF, false); x = x < t ? x : t;
    return (unsigned)__builtin_amdgcn_readlane((int)x, 63);
}

// Rectangular LSA (scipy SAP semantics), one 64-lane wave per batch.
// ALL state in registers; cross-lane via readlane/DPP. Zero LDS, zero barriers.
// Lane L owns columns j = L, L+64, ... (15 slots) and rows r = L, L+64 (2 slots).
__global__ __launch_bounds__(64) void lsa_kernel(const float* __restrict__ cost,
                                                 const int* __restrict__ nvalid,
                                                 int* __restrict__ match_q) {
    int b = blockIdx.x;
    int lane = threadIdx.x;
    int n = nvalid[b];
    const float* cbase = cost + (size_t)b * GG * QQ;

    float v[NSLOT], sh[NSLOT];
    int path_r[NSLOT], r4c_r[NSLOT];
    float u_r[2], srv_r[2];
    int c4r_r[2];
    unsigned valid_mask = 0x3FFFu | ((lane < QQ - 14 * 64) ? 0x4000u : 0u);

#pragma unroll
    for (int s = 0; s < NSLOT; ++s) { v[s] = 0.f; r4c_r[s] = -1; }
#pragma unroll
    for (int s = 0; s < 2; ++s) { u_r[s] = 0.f; c4r_r[s] = -1; srv_r[s] = 0.f; }

    for (int cur = 0; cur < n; ++cur) {
        unsigned sc = 0, srm = 0;
#pragma unroll
        for (int s = 0; s < NSLOT; ++s) sh[s] = INFINITY;

        int i2 = cur;
        float minv = 0.f;
        int sink = -1;
        for (int pop = 0; pop < 2 * GG && sink < 0; ++pop) {
            // ui = u[i2] (uniform): select slot then readlane
            float uv = (i2 >> 6) ? u_r[1] : u_r[0];
            float ui = __uint_as_float(
                (unsigned)__builtin_amdgcn_readlane((int)__float_as_uint(uv), i2 & 63));
            const float* crow = cbase + (size_t)i2 * QQ;
            float cv[NSLOT];
#pragma unroll
            for (int s = 0; s < NSLOT; ++s) {
                int j = s * 64 + lane;
                cv[s] = (s < NSLOT - 1 || ((valid_mask >> s) & 1u)) ? crow[j] : 0.f;
            }
            unsigned act = valid_mask & ~sc;
            unsigned lkey = 0xFFFFFFFFu;
            int lslot = 0;
#pragma unroll
            for (int s = 0; s < NSLOT; ++s) {
                if ((act >> s) & 1u) {
                    float r = minv + cv[s] - ui - v[s];
                    if (r < sh[s]) { sh[s] = r; path_r[s] = i2; }
                    unsigned key = f2key(sh[s]);
                    if (key < lkey) { lkey = key; lslot = s; }
                }
            }
            unsigned gkey = wave_min_u32(lkey);
            unsigned cand = (lkey == gkey) ? (unsigned)(lslot * 64 + lane) : 0xFFFFFFFFu;
            int lj = (int)wave_min_u32(cand);  // lowest column among ties
            minv = key2f(gkey);
            if (lane == (lj & 63)) sc |= (1u << (lj >> 6));
            // r4c = row4col[lj]
            int rslot = lj >> 6, rlane = lj & 63;
            int rv = -1;
#pragma unroll
            for (int s = 0; s < NSLOT; ++s)
                if (s == rslot) rv = r4c_r[s];
            int r4c = __builtin_amdgcn_readlane(rv, rlane);
            if (r4c == -1) {
                sink = lj;
            } else {
                i2 = r4c;
                if (lane == (i2 & 63)) {
#pragma unroll
                    for (int s = 0; s < 2; ++s)
                        if (s == (i2 >> 6)) { srm |= (1u << s); srv_r[s] = minv; }
                }
            }
        }
        if (sink < 0) break;  // safety (cannot happen)
        // dual updates (reference order: before augmentation)
        if (lane == (cur & 63)) {
#pragma unroll
            for (int s = 0; s < 2; ++s)
                if (s == (cur >> 6)) u_r[s] += minv;
        }
#pragma unroll
        for (int s = 0; s < 2; ++s)
            if ((srm >> s) & 1u) u_r[s] += minv - srv_r[s];
#pragma unroll
        for (int s = 0; s < NSLOT; ++s)
            if ((sc >> s) & 1u) v[s] -= (minv - sh[s]);
        // augment (wave-cooperative, uniform walk)
        int j = sink;
        while (true) {
            int pslot = j >> 6, plane = j & 63;
            int pv = 0;
#pragma unroll
            for (int s = 0; s < NSLOT; ++s)
                if (s == pslot) pv = path_r[s];
            int pi = __builtin_amdgcn_readlane(pv, plane);
            if (lane == plane) {
#pragma unroll
                for (int s = 0; s < NSLOT; ++s)
                    if (s == pslot) r4c_r[s] = pi;
            }
            int cslot = pi >> 6, clane = pi & 63;
            int cvv = 0;
#pragma unroll
            for (int s = 0; s < 2; ++s)
                if (s == cslot) cvv = c4r_r[s];
            int nj = __builtin_amdgcn_readlane(cvv, clane);
            if (lane == clane) {
#pragma unroll
                for (int s = 0; s < 2; ++s)
                    if (s == cslot) c4r_r[s] = j;
            }
            j = nj;
            if (pi == cur) break;
        }
    }
#pragma unroll
    for (int s = 0; s < 2; ++s) {
        int r = s * 64 + lane;
        if (r < n) match_q[b * GG + r] = c4r_r[s];
    }
}

// Per matched pair: CE adjustment, L1 sum, (1 - giou) sum.
__global__ void matched_kernel(const float* __restrict__ logits, const float* __restrict__ pboxes,
                               const float* __restrict__ gboxes, const int* __restrict__ glabels,
                               const float* __restrict__ lse, const int* __restrict__ valid_idx,
                               const int* __restrict__ nvalid, const int* __restrict__ match_q,
                               double* __restrict__ acc) {
    int t = blockIdx.x * blockDim.x + threadIdx.x;
    if (t >= BB * GG) return;
    int b = t / GG, k = t % GG;
    if (k >= nvalid[b]) return;
    int g = valid_idx[b * GG + k];
    int q = match_q[b * GG + k];
    if (q < 0 || q >= QQ) return;  // safety
    int label = glabels[b * GG + g];
    size_t ro = ((size_t)b * QQ + q) * CC;
    float ls = lse[b * QQ + q];
    float nll_lab = ls - logits[ro + label];
    float nll_no = ls - logits[ro + NCL];
    double ce_adj = 0.1 * (double)nll_lab - (double)nll_no;

    float4 pb = ((const float4*)pboxes)[b * QQ + q];
    float4 gb = ((const float4*)gboxes)[b * GG + g];
    float l1 = fabsf(pb.x - gb.x) + fabsf(pb.y - gb.y) + fabsf(pb.z - gb.z) + fabsf(pb.w - gb.w);

    float px0 = pb.x - 0.5f * pb.z, py0 = pb.y - 0.5f * pb.w;
    float px1 = pb.x + 0.5f * pb.z, py1 = pb.y + 0.5f * pb.w;
    float gx0 = gb.x - 0.5f * gb.z, gy0 = gb.y - 0.5f * gb.w;
    float gx1 = gb.x + 0.5f * gb.z, gy1 = gb.y + 0.5f * gb.w;
    float parea = (px1 - px0) * (py1 - py0);
    float garea = (gx1 - gx0) * (gy1 - gy0);
    float ltx = fmaxf(px0, gx0), lty = fmaxf(py0, gy0);
    float rbx = fminf(px1, gx1), rby = fminf(py1, gy1);
    float iw = fmaxf(rbx - ltx, 0.f), ih = fmaxf(rby - lty, 0.f);
    float inter = iw * ih;
    float uni = parea + garea - inter;
    float iou = inter / uni;
    float cx0 = fminf(px0, gx0), cy0 = fminf(py0, gy0);
    float cx1 = fmaxf(px1, gx1), cy1 = fmaxf(py1, gy1);
    float cw = fmaxf(cx1 - cx0, 0.f), ch = fmaxf(cy1 - cy0, 0.f);
    float ac = cw * ch;
    float giou = iou - (ac - uni) / ac;

    atomicAdd(&acc[1], ce_adj);
    atomicAdd(&acc[2], (double)l1);
    atomicAdd(&acc[3], 1.0 - (double)giou);
}

__global__ void final_kernel(const int* __restrict__ nvalid, const double* __restrict__ acc,
                             float* __restrict__ out) {
    if (blockIdx.x == 0 && threadIdx.x == 0) {
        int M = 0;
        for (int b = 0; b < BB; ++b) M += nvalid[b];
        double sum_w = (double)(BB * QQ) - 0.9 * (double)M;
        out[0] = (float)((acc[0] + acc[1]) / sum_w);
        out[1] = (float)(acc[2] / (4.0 * (double)M));
        out[2] = (float)(acc[3] / (double)M);
    }
}

extern "C" void kernel_launch(void* const* d_in, const int* in_sizes, int n_in,
                              void* d_out, int out_size, void* d_ws, size_t ws_size,
                              hipStream_t stream) {
    const float* logits = (const float*)d_in[0];
    const float* pboxes = (const float*)d_in[1];
    const int* glabels = (const int*)d_in[2];
    const float* gboxes = (const float*)d_in[3];
    float* out = (float*)d_out;

    char* ws = (char*)d_ws;
    float* cost = (float*)(ws + COST_OFF);
    float* lse = (float*)(ws + LSE_OFF);
    int* vidx = (int*)(ws + VIDX_OFF);
    int* nval = (int*)(ws + NV_OFF);
    int* mq = (int*)(ws + MQ_OFF);
    double* acc = (double*)(ws + ACC_OFF);

    hipMemsetAsync(acc, 0, 4 * sizeof(double), stream);
    compact_kernel<<<1, 128, 0, stream>>>(glabels, vidx, nval);
    lse_kernel<<<1024, 256, 0, stream>>>(logits, lse, acc);
    cost_kernel<<<BB * GG, 256, 0, stream>>>(logits, pboxes, gboxes, glabels, lse, vidx, nval, cost);
    lsa_kernel<<<BB, 64, 0, stream>>>(cost, nval, mq);
    matched_kernel<<<(BB * GG + 255) / 256, 256, 0, stream>>>(logits, pboxes, gboxes, glabels, lse,
                                                              vidx, nval, mq, acc);
    final_kernel<<<1, 1, 0, stream>>>(nval, acc, out);
}

// Round 4
// 326.094 us; speedup vs baseline: 2.3838x; 1.0057x over previous
//
#include <hip/hip_runtime.h>
#include <hip/hip_fp16.h>
#include <math.h>

#define BB 128
#define QQ 900
#define GG 80
#define CC 92
#define NCL 91
#define NSLOT 15  // ceil(QQ/64)

// ---------------- ws layout (bytes) ----------------
#define COST_OFF 0            // __half[BB*GG*QQ]  18,432,000 (region sized for fp32; fp16 fits)
#define LSE_OFF  36864000     // float[BB*QQ]
#define VIDX_OFF 37324800     // int[BB*GG]
#define NV_OFF   37365760     // int[BB]
#define MQ_OFF   37366272     // int[BB*GG]
#define ACC_OFF  37407232     // double[4]  [S_base, ce_adj, l1, giou]

// Per-batch compaction of valid gt indices (label < 91).
__global__ void compact_kernel(const int* __restrict__ glabels, int* __restrict__ valid_idx,
                               int* __restrict__ nvalid) {
    int b = blockIdx.x * blockDim.x + threadIdx.x;
    if (b >= BB) return;
    int cnt = 0;
    for (int g = 0; g < GG; ++g)
        if (glabels[b * GG + g] < NCL) valid_idx[b * GG + (cnt++)] = g;
    nvalid[b] = cnt;
}

// Grid-stride: one wave per (b,q) row. Computes lse AND accumulates the
// no-object CE base sum  sum(lse - logit[91]).
__global__ void lse_kernel(const float* __restrict__ logits, float* __restrict__ lse,
                           double* __restrict__ acc) {
    __shared__ double sd[4];
    int lane = threadIdx.x & 63;
    int wslot = threadIdx.x >> 6;
    int gwave = (blockIdx.x * blockDim.x + threadIdx.x) >> 6;
    int nwaves = (gridDim.x * blockDim.x) >> 6;
    double local = 0.0;
    for (int wid = gwave; wid < BB * QQ; wid += nwaves) {
        const float* row = logits + (size_t)wid * CC;
        float e0 = row[lane];
        float e1 = (lane < CC - 64) ? row[lane + 64] : -INFINITY;
        float mx = fmaxf(e0, e1);
#pragma unroll
        for (int off = 32; off; off >>= 1) mx = fmaxf(mx, __shfl_down(mx, off));
        mx = __shfl(mx, 0);
        float s = expf(e0 - mx) + ((lane < CC - 64) ? expf(e1 - mx) : 0.f);
#pragma unroll
        for (int off = 32; off; off >>= 1) s += __shfl_down(s, off);
        s = __shfl(s, 0);
        float l = mx + logf(s);
        float no = __shfl(e1, NCL - 64);  // lane 27 holds row[91]
        if (lane == 0) {
            lse[wid] = l;
            local += (double)l - (double)no;
        }
    }
    if (lane == 0) sd[wslot] = local;
    __syncthreads();
    if (threadIdx.x == 0) {
        double t = 0.0;
        for (int w = 0; w < 4; ++w) t += sd[w];
        atomicAdd(&acc[0], t);
    }
}

// One block per batch (grid=128 -> same XCD round-robin slot as lsa_kernel's
// block b, so the fp16 cost lines this block writes stay in that XCD's L2).
// Thread t owns queries q = t, t+512, ...; inner loop over valid gt rows k
// reuses the lane's 368-B logit row (L1-hot label gather).
__global__ __launch_bounds__(512) void cost_kernel(const float* __restrict__ logits,
                                                   const float* __restrict__ pboxes,
                                                   const float* __restrict__ gboxes,
                                                   const int* __restrict__ glabels,
                                                   const float* __restrict__ lse,
                                                   const int* __restrict__ valid_idx,
                                                   const int* __restrict__ nvalid,
                                                   __half* __restrict__ cost) {
    __shared__ int slab[GG];
    __shared__ float sgx0[GG], sgy0[GG], sgx1[GG], sgy1[GG], sgar[GG];
    __shared__ float sgcx[GG], sgcy[GG], sgcz[GG], sgcw[GG];
    int b = blockIdx.x;
    int n = nvalid[b];
    for (int k = threadIdx.x; k < n; k += 512) {
        int g = valid_idx[b * GG + k];
        slab[k] = glabels[b * GG + g];
        float4 gb = ((const float4*)gboxes)[b * GG + g];
        sgcx[k] = gb.x; sgcy[k] = gb.y; sgcz[k] = gb.z; sgcw[k] = gb.w;
        float gx0 = gb.x - 0.5f * gb.z, gy0 = gb.y - 0.5f * gb.w;
        float gx1 = gb.x + 0.5f * gb.z, gy1 = gb.y + 0.5f * gb.w;
        sgx0[k] = gx0; sgy0[k] = gy0; sgx1[k] = gx1; sgy1[k] = gy1;
        sgar[k] = (gx1 - gx0) * (gy1 - gy0);
    }
    __syncthreads();
    for (int q = threadIdx.x; q < QQ; q += 512) {
        float4 pb = ((const float4*)pboxes)[b * QQ + q];
        float px0 = pb.x - 0.5f * pb.z, py0 = pb.y - 0.5f * pb.w;
        float px1 = pb.x + 0.5f * pb.z, py1 = pb.y + 0.5f * pb.w;
        float parea = (px1 - px0) * (py1 - py0);
        float lse_q = lse[b * QQ + q];
        const float* lrow = logits + ((size_t)(b * QQ) + q) * CC;
        for (int k = 0; k < n; ++k) {
            float l1 = fabsf(pb.x - sgcx[k]) + fabsf(pb.y - sgcy[k]) +
                       fabsf(pb.z - sgcz[k]) + fabsf(pb.w - sgcw[k]);
            float ltx = fmaxf(px0, sgx0[k]), lty = fmaxf(py0, sgy0[k]);
            float rbx = fminf(px1, sgx1[k]), rby = fminf(py1, sgy1[k]);
            float iw = fmaxf(rbx - ltx, 0.f), ih = fmaxf(rby - lty, 0.f);
            float inter = iw * ih;
            float uni = parea + sgar[k] - inter;
            float iou = inter / uni;
            float cx0 = fminf(px0, sgx0[k]), cy0 = fminf(py0, sgy0[k]);
            float cx1 = fmaxf(px1, sgx1[k]), cy1 = fmaxf(py1, sgy1[k]);
            float cw = fmaxf(cx1 - cx0, 0.f), ch = fmaxf(cy1 - cy0, 0.f);
            float ac = cw * ch;
            float giou = iou - (ac - uni) / ac;
            float cls = lse_q - lrow[slab[k]];
            cost[((size_t)(b * GG + k)) * QQ + q] = __float2half_rn(5.f * l1 + cls - 2.f * giou);
        }
    }
}

// Monotone float<->u32 key map (unsigned compare == float compare).
__device__ __forceinline__ unsigned f2key(float f) {
    unsigned b = __float_as_uint(f);
    return b ^ (unsigned)(((int)b >> 31) | (int)0x80000000);
}
__device__ __forceinline__ float key2f(unsigned k) {
    unsigned b = (k & 0x80000000u) ? (k ^ 0x80000000u) : ~k;
    return __uint_as_float(b);
}

// Wave64 min-reduce via DPP; returns uniform min (readlane 63).
__device__ __forceinline__ unsigned wave_min_u32(unsigned x) {
    unsigned t;
    t = (unsigned)__builtin_amdgcn_update_dpp((int)x, (int)x, 0x111, 0xF, 0xF, false); x = x < t ? x : t;
    t = (unsigned)__builtin_amdgcn_update_dpp((int)x, (int)x, 0x112, 0xF, 0xF, false); x = x < t ? x : t;
    t = (unsigned)__builtin_amdgcn_update_dpp((int)x, (int)x, 0x114, 0xF, 0xF, false); x = x < t ? x : t;
    t = (unsigned)__builtin_amdgcn_update_dpp((int)x, (int)x, 0x118, 0xF, 0xF, false); x = x < t ? x : t;
    t = (unsigned)__builtin_amdgcn_update_dpp((int)x, (int)x, 0x142, 0xF, 0xF, false); x = x < t ? x : t;
    t = (unsigned)__builtin_amdgcn_update_dpp((int)x, (int)x, 0x143, 0xF, 0xF, false); x = x < t ? x : t;
    return (unsigned)__builtin_amdgcn_readlane((int)x, 63);
}

// Rectangular LSA (scipy SAP semantics), one 64-lane wave per batch.
// ALL state in registers; cross-lane via readlane/DPP. Zero LDS, zero barriers.
// Cost rows are fp16 and L2-resident (written by the same-XCD cost block).
__global__ __launch_bounds__(64) void lsa_kernel(const __half* __restrict__ cost,
                                                 const int* __restrict__ nvalid,
                                                 int* __restrict__ match_q) {
    int b = blockIdx.x;
    int lane = threadIdx.x;
    int n = nvalid[b];
    const __half* cbase = cost + (size_t)b * GG * QQ;

    float v[NSLOT], sh[NSLOT];
    int path_r[NSLOT], r4c_r[NSLOT];
    float u_r[2], srv_r[2];
    int c4r_r[2];
    unsigned valid_mask = 0x3FFFu | ((lane < QQ - 14 * 64) ? 0x4000u : 0u);

#pragma unroll
    for (int s = 0; s < NSLOT; ++s) { v[s] = 0.f; r4c_r[s] = -1; }
#pragma unroll
    for (int s = 0; s < 2; ++s) { u_r[s] = 0.f; c4r_r[s] = -1; srv_r[s] = 0.f; }

    for (int cur = 0; cur < n; ++cur) {
        unsigned sc = 0, srm = 0;
#pragma unroll
        for (int s = 0; s < NSLOT; ++s) sh[s] = INFINITY;

        int i2 = cur;
        float minv = 0.f;
        int sink = -1;
        for (int pop = 0; pop < 2 * GG && sink < 0; ++pop) {
            // ui = u[i2] (uniform): select slot then readlane
            float uv = (i2 >> 6) ? u_r[1] : u_r[0];
            float ui = __uint_as_float(
                (unsigned)__builtin_amdgcn_readlane((int)__float_as_uint(uv), i2 & 63));
            const __half* crow = cbase + (size_t)i2 * QQ;
            float cv[NSLOT];
#pragma unroll
            for (int s = 0; s < NSLOT; ++s) {
                int j = s * 64 + lane;
                cv[s] = (s < NSLOT - 1 || ((valid_mask >> s) & 1u)) ? __half2float(crow[j]) : 0.f;
            }
            unsigned act = valid_mask & ~sc;
            unsigned lkey = 0xFFFFFFFFu;
            int lslot = 0;
#pragma unroll
            for (int s = 0; s < NSLOT; ++s) {
                if ((act >> s) & 1u) {
                    float r = minv + cv[s] - ui - v[s];
                    if (r < sh[s]) { sh[s] = r; path_r[s] = i2; }
                    unsigned key = f2key(sh[s]);
                    if (key < lkey) { lkey = key; lslot = s; }
                }
            }
            unsigned gkey = wave_min_u32(lkey);
            unsigned cand = (lkey == gkey) ? (unsigned)(lslot * 64 + lane) : 0xFFFFFFFFu;
            int lj = (int)wave_min_u32(cand);  // lowest column among ties
            minv = key2f(gkey);
            if (lane == (lj & 63)) sc |= (1u << (lj >> 6));
            // r4c = row4col[lj]
            int rslot = lj >> 6, rlane = lj & 63;
            int rv = -1;
#pragma unroll
            for (int s = 0; s < NSLOT; ++s)
                if (s == rslot) rv = r4c_r[s];
            int r4c = __builtin_amdgcn_readlane(rv, rlane);
            if (r4c == -1) {
                sink = lj;
            } else {
                i2 = r4c;
                if (lane == (i2 & 63)) {
#pragma unroll
                    for (int s = 0; s < 2; ++s)
                        if (s == (i2 >> 6)) { srm |= (1u << s); srv_r[s] = minv; }
                }
            }
        }
        if (sink < 0) break;  // safety (cannot happen)
        // dual updates (reference order: before augmentation)
        if (lane == (cur & 63)) {
#pragma unroll
            for (int s = 0; s < 2; ++s)
                if (s == (cur >> 6)) u_r[s] += minv;
        }
#pragma unroll
        for (int s = 0; s < 2; ++s)
            if ((srm >> s) & 1u) u_r[s] += minv - srv_r[s];
#pragma unroll
        for (int s = 0; s < NSLOT; ++s)
            if ((sc >> s) & 1u) v[s] -= (minv - sh[s]);
        // augment (wave-cooperative, uniform walk)
        int j = sink;
        while (true) {
            int pslot = j >> 6, plane = j & 63;
            int pv = 0;
#pragma unroll
            for (int s = 0; s < NSLOT; ++s)
                if (s == pslot) pv = path_r[s];
            int pi = __builtin_amdgcn_readlane(pv, plane);
            if (lane == plane) {
#pragma unroll
                for (int s = 0; s < NSLOT; ++s)
                    if (s == pslot) r4c_r[s] = pi;
            }
            int cslot = pi >> 6, clane = pi & 63;
            int cvv = 0;
#pragma unroll
            for (int s = 0; s < 2; ++s)
                if (s == cslot) cvv = c4r_r[s];
            int nj = __builtin_amdgcn_readlane(cvv, clane);
            if (lane == clane) {
#pragma unroll
                for (int s = 0; s < 2; ++s)
                    if (s == cslot) c4r_r[s] = j;
            }
            j = nj;
            if (pi == cur) break;
        }
    }
#pragma unroll
    for (int s = 0; s < 2; ++s) {
        int r = s * 64 + lane;
        if (r < n) match_q[b * GG + r] = c4r_r[s];
    }
}

// Per matched pair: CE adjustment, L1 sum, (1 - giou) sum.
__global__ void matched_kernel(const float* __restrict__ logits, const float* __restrict__ pboxes,
                               const float* __restrict__ gboxes, const int* __restrict__ glabels,
                               const float* __restrict__ lse, const int* __restrict__ valid_idx,
                               const int* __restrict__ nvalid, const int* __restrict__ match_q,
                               double* __restrict__ acc) {
    int t = blockIdx.x * blockDim.x + threadIdx.x;
    if (t >= BB * GG) return;
    int b = t / GG, k = t % GG;
    if (k >= nvalid[b]) return;
    int g = valid_idx[b * GG + k];
    int q = match_q[b * GG + k];
    if (q < 0 || q >= QQ) return;  // safety
    int label = glabels[b * GG + g];
    size_t ro = ((size_t)b * QQ + q) * CC;
    float ls = lse[b * QQ + q];
    float nll_lab = ls - logits[ro + label];
    float nll_no = ls - logits[ro + NCL];
    double ce_adj = 0.1 * (double)nll_lab - (double)nll_no;

    float4 pb = ((const float4*)pboxes)[b * QQ + q];
    float4 gb = ((const float4*)gboxes)[b * GG + g];
    float l1 = fabsf(pb.x - gb.x) + fabsf(pb.y - gb.y) + fabsf(pb.z - gb.z) + fabsf(pb.w - gb.w);

    float px0 = pb.x - 0.5f * pb.z, py0 = pb.y - 0.5f * pb.w;
    float px1 = pb.x + 0.5f * pb.z, py1 = pb.y + 0.5f * pb.w;
    float gx0 = gb.x - 0.5f * gb.z, gy0 = gb.y - 0.5f * gb.w;
    float gx1 = gb.x + 0.5f * gb.z, gy1 = gb.y + 0.5f * gb.w;
    float parea = (px1 - px0) * (py1 - py0);
    float garea = (gx1 - gx0) * (gy1 - gy0);
    float ltx = fmaxf(px0, gx0), lty = fmaxf(py0, gy0);
    float rbx = fminf(px1, gx1), rby = fminf(py1, gy1);
    float iw = fmaxf(rbx - ltx, 0.f), ih = fmaxf(rby - lty, 0.f);
    float inter = iw * ih;
    float uni = parea + garea - inter;
    float iou = inter / uni;
    float cx0 = fminf(px0, gx0), cy0 = fminf(py0, gy0);
    float cx1 = fmaxf(px1, gx1), cy1 = fmaxf(py1, gy1);
    float cw = fmaxf(cx1 - cx0, 0.f), ch = fmaxf(cy1 - cy0, 0.f);
    float ac = cw * ch;
    float giou = iou - (ac - uni) / ac;

    atomicAdd(&acc[1], ce_adj);
    atomicAdd(&acc[2], (double)l1);
    atomicAdd(&acc[3], 1.0 - (double)giou);
}

__global__ void final_kernel(const int* __restrict__ nvalid, const double* __restrict__ acc,
                             float* __restrict__ out) {
    if (blockIdx.x == 0 && threadIdx.x == 0) {
        int M = 0;
        for (int b = 0; b < BB; ++b) M += nvalid[b];
        double sum_w = (double)(BB * QQ) - 0.9 * (double)M;
        out[0] = (float)((acc[0] + acc[1]) / sum_w);
        out[1] = (float)(acc[2] / (4.0 * (double)M));
        out[2] = (float)(acc[3] / (double)M);
    }
}

extern "C" void kernel_launch(void* const* d_in, const int* in_sizes, int n_in,
                              void* d_out, int out_size, void* d_ws, size_t ws_size,
                              hipStream_t stream) {
    const float* logits = (const float*)d_in[0];
    const float* pboxes = (const float*)d_in[1];
    const int* glabels = (const int*)d_in[2];
    const float* gboxes = (const float*)d_in[3];
    float* out = (float*)d_out;

    char* ws = (char*)d_ws;
    __half* cost = (__half*)(ws + COST_OFF);
    float* lse = (float*)(ws + LSE_OFF);
    int* vidx = (int*)(ws + VIDX_OFF);
    int* nval = (int*)(ws + NV_OFF);
    int* mq = (int*)(ws + MQ_OFF);
    double* acc = (double*)(ws + ACC_OFF);

    hipMemsetAsync(acc, 0, 4 * sizeof(double), stream);
    compact_kernel<<<1, 128, 0, stream>>>(glabels, vidx, nval);
    lse_kernel<<<1024, 256, 0, stream>>>(logits, lse, acc);
    cost_kernel<<<BB, 512, 0, stream>>>(logits, pboxes, gboxes, glabels, lse, vidx, nval, cost);
    lsa_kernel<<<BB, 64, 0, stream>>>(cost, nval, mq);
    matched_kernel<<<(BB * GG + 255) / 256, 256, 0, stream>>>(logits, pboxes, gboxes, glabels, lse,
                                                              vidx, nval, mq, acc);
    final_kernel<<<1, 1, 0, stream>>>(nval, acc, out);
}

// Round 5
// 308.234 us; speedup vs baseline: 2.5219x; 1.0579x over previous
//
#include <hip/hip_runtime.h>
#include <hip/hip_fp16.h>
#include <math.h>

#define BB 128
#define QQ 900
#define GG 80
#define CC 92
#define NCL 91
#define NSLOT 15  // ceil(QQ/64)

// ---------------- ws layout (bytes) ----------------
#define COST_OFF 0            // __half[BB*GG*QQ]  18,432,000
#define LSE_OFF  36864000     // float[BB*QQ]
#define VIDX_OFF 37324800     // int[BB*GG]
#define NV_OFF   37365760     // int[BB]
#define MQ_OFF   37366272     // int[BB*GG]
#define ACC_OFF  37407232     // double[4]  [S_base, ce_adj, l1, giou]

// One wave per batch: ballot/popc compaction of valid gt indices (label < 91).
__global__ __launch_bounds__(64) void compact_kernel(const int* __restrict__ glabels,
                                                     int* __restrict__ valid_idx,
                                                     int* __restrict__ nvalid) {
    int b = blockIdx.x;
    int lane = threadIdx.x;
    int l0 = glabels[b * GG + lane];             // lanes 0..63 cover g=0..63
    bool v0 = l0 < NCL;
    bool v1 = false;
    if (lane < GG - 64) v1 = glabels[b * GG + 64 + lane] < NCL;  // g=64..79
    unsigned long long m0 = __ballot(v0);
    unsigned long long m1 = __ballot(v1);
    int c0 = __popcll(m0);
    unsigned long long lower = (lane == 0) ? 0ULL : (~0ULL >> (64 - lane));
    if (v0) valid_idx[b * GG + __popcll(m0 & lower)] = lane;
    if (v1) valid_idx[b * GG + c0 + __popcll(m1 & lower)] = 64 + lane;
    if (lane == 0) nvalid[b] = c0 + __popcll(m1);
}

// Grid-stride: one wave per (b,q) row. Computes lse AND accumulates the
// no-object CE base sum  sum(lse - logit[91]).
__global__ void lse_kernel(const float* __restrict__ logits, float* __restrict__ lse,
                           double* __restrict__ acc) {
    __shared__ double sd[4];
    int lane = threadIdx.x & 63;
    int wslot = threadIdx.x >> 6;
    int gwave = (blockIdx.x * blockDim.x + threadIdx.x) >> 6;
    int nwaves = (gridDim.x * blockDim.x) >> 6;
    double local = 0.0;
    for (int wid = gwave; wid < BB * QQ; wid += nwaves) {
        const float* row = logits + (size_t)wid * CC;
        float e0 = row[lane];
        float e1 = (lane < CC - 64) ? row[lane + 64] : -INFINITY;
        float mx = fmaxf(e0, e1);
#pragma unroll
        for (int off = 32; off; off >>= 1) mx = fmaxf(mx, __shfl_down(mx, off));
        mx = __shfl(mx, 0);
        float s = expf(e0 - mx) + ((lane < CC - 64) ? expf(e1 - mx) : 0.f);
#pragma unroll
        for (int off = 32; off; off >>= 1) s += __shfl_down(s, off);
        s = __shfl(s, 0);
        float l = mx + logf(s);
        float no = __shfl(e1, NCL - 64);  // lane 27 holds row[91]
        if (lane == 0) {
            lse[wid] = l;
            local += (double)l - (double)no;
        }
    }
    if (lane == 0) sd[wslot] = local;
    __syncthreads();
    if (threadIdx.x == 0) {
        double t = 0.0;
        for (int w = 0; w < 4; ++w) t += sd[w];
        atomicAdd(&acc[0], t);
    }
}

// One block per batch; thread t owns queries q = t, t+512. Inner loop over
// valid gt rows k reuses the lane's 368-B logit row (L1-hot label gather).
__global__ __launch_bounds__(512) void cost_kernel(const float* __restrict__ logits,
                                                   const float* __restrict__ pboxes,
                                                   const float* __restrict__ gboxes,
                                                   const int* __restrict__ glabels,
                                                   const float* __restrict__ lse,
                                                   const int* __restrict__ valid_idx,
                                                   const int* __restrict__ nvalid,
                                                   __half* __restrict__ cost) {
    __shared__ int slab[GG];
    __shared__ float sgx0[GG], sgy0[GG], sgx1[GG], sgy1[GG], sgar[GG];
    __shared__ float sgcx[GG], sgcy[GG], sgcz[GG], sgcw[GG];
    int b = blockIdx.x;
    int n = nvalid[b];
    for (int k = threadIdx.x; k < n; k += 512) {
        int g = valid_idx[b * GG + k];
        slab[k] = glabels[b * GG + g];
        float4 gb = ((const float4*)gboxes)[b * GG + g];
        sgcx[k] = gb.x; sgcy[k] = gb.y; sgcz[k] = gb.z; sgcw[k] = gb.w;
        float gx0 = gb.x - 0.5f * gb.z, gy0 = gb.y - 0.5f * gb.w;
        float gx1 = gb.x + 0.5f * gb.z, gy1 = gb.y + 0.5f * gb.w;
        sgx0[k] = gx0; sgy0[k] = gy0; sgx1[k] = gx1; sgy1[k] = gy1;
        sgar[k] = (gx1 - gx0) * (gy1 - gy0);
    }
    __syncthreads();
    for (int q = threadIdx.x; q < QQ; q += 512) {
        float4 pb = ((const float4*)pboxes)[b * QQ + q];
        float px0 = pb.x - 0.5f * pb.z, py0 = pb.y - 0.5f * pb.w;
        float px1 = pb.x + 0.5f * pb.z, py1 = pb.y + 0.5f * pb.w;
        float parea = (px1 - px0) * (py1 - py0);
        float lse_q = lse[b * QQ + q];
        const float* lrow = logits + ((size_t)(b * QQ) + q) * CC;
        for (int k = 0; k < n; ++k) {
            float l1 = fabsf(pb.x - sgcx[k]) + fabsf(pb.y - sgcy[k]) +
                       fabsf(pb.z - sgcz[k]) + fabsf(pb.w - sgcw[k]);
            float ltx = fmaxf(px0, sgx0[k]), lty = fmaxf(py0, sgy0[k]);
            float rbx = fminf(px1, sgx1[k]), rby = fminf(py1, sgy1[k]);
            float iw = fmaxf(rbx - ltx, 0.f), ih = fmaxf(rby - lty, 0.f);
            float inter = iw * ih;
            float uni = parea + sgar[k] - inter;
            float iou = inter / uni;
            float cx0 = fminf(px0, sgx0[k]), cy0 = fminf(py0, sgy0[k]);
            float cx1 = fmaxf(px1, sgx1[k]), cy1 = fmaxf(py1, sgy1[k]);
            float cw = fmaxf(cx1 - cx0, 0.f), ch = fmaxf(cy1 - cy0, 0.f);
            float ac = cw * ch;
            float giou = iou - (ac - uni) / ac;
            float cls = lse_q - lrow[slab[k]];
            cost[((size_t)(b * GG + k)) * QQ + q] = __float2half_rn(5.f * l1 + cls - 2.f * giou);
        }
    }
}

// Monotone float<->u32 key map (unsigned compare == float compare).
__device__ __forceinline__ unsigned f2key(float f) {
    unsigned b = __float_as_uint(f);
    return b ^ (unsigned)(((int)b >> 31) | (int)0x80000000);
}
__device__ __forceinline__ float key2f(unsigned k) {
    unsigned b = (k & 0x80000000u) ? (k ^ 0x80000000u) : ~k;
    return __uint_as_float(b);
}

// Wave64 min-reduce via DPP; returns uniform min (readlane 63).
__device__ __forceinline__ unsigned wave_min_u32(unsigned x) {
    unsigned t;
    t = (unsigned)__builtin_amdgcn_update_dpp((int)x, (int)x, 0x111, 0xF, 0xF, false); x = x < t ? x : t;
    t = (unsigned)__builtin_amdgcn_update_dpp((int)x, (int)x, 0x112, 0xF, 0xF, false); x = x < t ? x : t;
    t = (unsigned)__builtin_amdgcn_update_dpp((int)x, (int)x, 0x114, 0xF, 0xF, false); x = x < t ? x : t;
    t = (unsigned)__builtin_amdgcn_update_dpp((int)x, (int)x, 0x118, 0xF, 0xF, false); x = x < t ? x : t;
    t = (unsigned)__builtin_amdgcn_update_dpp((int)x, (int)x, 0x142, 0xF, 0xF, false); x = x < t ? x : t;
    t = (unsigned)__builtin_amdgcn_update_dpp((int)x, (int)x, 0x143, 0xF, 0xF, false); x = x < t ? x : t;
    return (unsigned)__builtin_amdgcn_readlane((int)x, 63);
}

// Rectangular LSA (scipy SAP semantics), one 64-lane wave per batch.
// ALL state in registers; cross-lane via readlane/DPP. Zero LDS, zero barriers.
// __launch_bounds__(64, 1): min 1 wave/EU -> full 512-VGPR budget so the
// 5x15-slot arrays stay in VGPRs (the default heuristic capped at 48 VGPRs
// and spilled them to scratch -> ~4.5k cyc/pop. That was R4's stall.)
__global__ __launch_bounds__(64, 1) void lsa_kernel(const __half* __restrict__ cost,
                                                    const int* __restrict__ nvalid,
                                                    int* __restrict__ match_q) {
    int b = blockIdx.x;
    int lane = threadIdx.x;
    int n = nvalid[b];
    const __half* cbase = cost + (size_t)b * GG * QQ;

    float v[NSLOT], sh[NSLOT];
    int path_r[NSLOT], r4c_r[NSLOT];
    float u_r[2], srv_r[2];
    int c4r_r[2];
    unsigned valid_mask = 0x3FFFu | ((lane < QQ - 14 * 64) ? 0x4000u : 0u);

#pragma unroll
    for (int s = 0; s < NSLOT; ++s) { v[s] = 0.f; r4c_r[s] = -1; }
#pragma unroll
    for (int s = 0; s < 2; ++s) { u_r[s] = 0.f; c4r_r[s] = -1; srv_r[s] = 0.f; }

    for (int cur = 0; cur < n; ++cur) {
        unsigned sc = 0, srm = 0;
#pragma unroll
        for (int s = 0; s < NSLOT; ++s) sh[s] = INFINITY;

        int i2 = cur;
        float minv = 0.f;
        int sink = -1;
        for (int pop = 0; pop < 2 * GG && sink < 0; ++pop) {
            // ui = u[i2] (uniform): select slot then readlane
            float uv = (i2 >> 6) ? u_r[1] : u_r[0];
            float ui = __uint_as_float(
                (unsigned)__builtin_amdgcn_readlane((int)__float_as_uint(uv), i2 & 63));
            const __half* crow = cbase + (size_t)i2 * QQ;
            float cv[NSLOT];
#pragma unroll
            for (int s = 0; s < NSLOT; ++s) {
                int j = s * 64 + lane;
                cv[s] = (s < NSLOT - 1 || ((valid_mask >> s) & 1u)) ? __half2float(crow[j]) : 0.f;
            }
            unsigned act = valid_mask & ~sc;
            unsigned lkey = 0xFFFFFFFFu;
            int lslot = 0;
#pragma unroll
            for (int s = 0; s < NSLOT; ++s) {
                if ((act >> s) & 1u) {
                    float r = minv + cv[s] - ui - v[s];
                    if (r < sh[s]) { sh[s] = r; path_r[s] = i2; }
                    unsigned key = f2key(sh[s]);
                    if (key < lkey) { lkey = key; lslot = s; }
                }
            }
            unsigned gkey = wave_min_u32(lkey);
            unsigned cand = (lkey == gkey) ? (unsigned)(lslot * 64 + lane) : 0xFFFFFFFFu;
            int lj = (int)wave_min_u32(cand);  // lowest column among ties
            minv = key2f(gkey);
            if (lane == (lj & 63)) sc |= (1u << (lj >> 6));
            // r4c = row4col[lj]
            int rslot = lj >> 6, rlane = lj & 63;
            int rv = -1;
#pragma unroll
            for (int s = 0; s < NSLOT; ++s)
                if (s == rslot) rv = r4c_r[s];
            int r4c = __builtin_amdgcn_readlane(rv, rlane);
            if (r4c == -1) {
                sink = lj;
            } else {
                i2 = r4c;
                if (lane == (i2 & 63)) {
#pragma unroll
                    for (int s = 0; s < 2; ++s)
                        if (s == (i2 >> 6)) { srm |= (1u << s); srv_r[s] = minv; }
                }
            }
        }
        if (sink < 0) break;  // safety (cannot happen: pops/phase <= cur+1)
        // dual updates (reference order: before augmentation)
        if (lane == (cur & 63)) {
#pragma unroll
            for (int s = 0; s < 2; ++s)
                if (s == (cur >> 6)) u_r[s] += minv;
        }
#pragma unroll
        for (int s = 0; s < 2; ++s)
            if ((srm >> s) & 1u) u_r[s] += minv - srv_r[s];
#pragma unroll
        for (int s = 0; s < NSLOT; ++s)
            if ((sc >> s) & 1u) v[s] -= (minv - sh[s]);
        // augment (wave-cooperative, uniform walk)
        int j = sink;
        while (true) {
            int pslot = j >> 6, plane = j & 63;
            int pv = 0;
#pragma unroll
            for (int s = 0; s < NSLOT; ++s)
                if (s == pslot) pv = path_r[s];
            int pi = __builtin_amdgcn_readlane(pv, plane);
            if (lane == plane) {
#pragma unroll
                for (int s = 0; s < NSLOT; ++s)
                    if (s == pslot) r4c_r[s] = pi;
            }
            int cslot = pi >> 6, clane = pi & 63;
            int cvv = 0;
#pragma unroll
            for (int s = 0; s < 2; ++s)
                if (s == cslot) cvv = c4r_r[s];
            int nj = __builtin_amdgcn_readlane(cvv, clane);
            if (lane == clane) {
#pragma unroll
                for (int s = 0; s < 2; ++s)
                    if (s == cslot) c4r_r[s] = j;
            }
            j = nj;
            if (pi == cur) break;
        }
    }
#pragma unroll
    for (int s = 0; s < 2; ++s) {
        int r = s * 64 + lane;
        if (r < n) match_q[b * GG + r] = c4r_r[s];
    }
}

// Per matched pair: CE adjustment, L1 sum, (1 - giou) sum.
// Wave-level shfl reduction first, ONE fp64 atomic triple per wave
// (was 10240 threads x 3 atomics on the same 3 addresses = CAS storm).
__global__ void matched_kernel(const float* __restrict__ logits, const float* __restrict__ pboxes,
                               const float* __restrict__ gboxes, const int* __restrict__ glabels,
                               const float* __restrict__ lse, const int* __restrict__ valid_idx,
                               const int* __restrict__ nvalid, const int* __restrict__ match_q,
                               double* __restrict__ acc) {
    int t = blockIdx.x * blockDim.x + threadIdx.x;
    int lane = threadIdx.x & 63;
    bool ok = t < BB * GG;
    int b = ok ? t / GG : 0;
    int k = ok ? t % GG : 0;
    ok = ok && (k < nvalid[b]);
    int g = ok ? valid_idx[b * GG + k] : 0;
    int q = ok ? match_q[b * GG + k] : 0;
    if (q < 0 || q >= QQ) { ok = false; q = 0; }
    int label = ok ? glabels[b * GG + g] : 0;
    if (label < 0 || label >= CC) label = 0;

    size_t ro = ((size_t)b * QQ + q) * CC;
    float ls = lse[b * QQ + q];
    float nll_lab = ls - logits[ro + label];
    float nll_no = ls - logits[ro + NCL];
    double ce_adj = 0.1 * (double)nll_lab - (double)nll_no;

    float4 pb = ((const float4*)pboxes)[b * QQ + q];
    float4 gb = ((const float4*)gboxes)[b * GG + g];
    float l1 = fabsf(pb.x - gb.x) + fabsf(pb.y - gb.y) + fabsf(pb.z - gb.z) + fabsf(pb.w - gb.w);

    float px0 = pb.x - 0.5f * pb.z, py0 = pb.y - 0.5f * pb.w;
    float px1 = pb.x + 0.5f * pb.z, py1 = pb.y + 0.5f * pb.w;
    float gx0 = gb.x - 0.5f * gb.z, gy0 = gb.y - 0.5f * gb.w;
    float gx1 = gb.x + 0.5f * gb.z, gy1 = gb.y + 0.5f * gb.w;
    float parea = (px1 - px0) * (py1 - py0);
    float garea = (gx1 - gx0) * (gy1 - gy0);
    float ltx = fmaxf(px0, gx0), lty = fmaxf(py0, gy0);
    float rbx = fminf(px1, gx1), rby = fminf(py1, gy1);
    float iw = fmaxf(rbx - ltx, 0.f), ih = fmaxf(rby - lty, 0.f);
    float inter = iw * ih;
    float uni = parea + garea - inter;
    float iou = inter / uni;
    float cx0 = fminf(px0, gx0), cy0 = fminf(py0, gy0);
    float cx1 = fmaxf(px1, gx1), cy1 = fmaxf(py1, gy1);
    float cw = fmaxf(cx1 - cx0, 0.f), ch = fmaxf(cy1 - cy0, 0.f);
    float ac = cw * ch;
    float giou = iou - (ac - uni) / ac;

    double ce = ok ? ce_adj : 0.0;
    double dl1 = ok ? (double)l1 : 0.0;
    double dgi = ok ? (1.0 - (double)giou) : 0.0;
#pragma unroll
    for (int off = 32; off; off >>= 1) {
        ce += __shfl_down(ce, off);
        dl1 += __shfl_down(dl1, off);
        dgi += __shfl_down(dgi, off);
    }
    if (lane == 0) {
        atomicAdd(&acc[1], ce);
        atomicAdd(&acc[2], dl1);
        atomicAdd(&acc[3], dgi);
    }
}

// One wave: reduce nvalid -> M, compute the three losses.
__global__ __launch_bounds__(64) void final_kernel(const int* __restrict__ nvalid,
                                                   const double* __restrict__ acc,
                                                   float* __restrict__ out) {
    int lane = threadIdx.x;
    int m = nvalid[lane] + nvalid[64 + lane];  // BB = 128
#pragma unroll
    for (int off = 32; off; off >>= 1) m += __shfl_down(m, off);
    if (lane == 0) {
        double M = (double)m;
        double sum_w = (double)(BB * QQ) - 0.9 * M;
        out[0] = (float)((acc[0] + acc[1]) / sum_w);
        out[1] = (float)(acc[2] / (4.0 * M));
        out[2] = (float)(acc[3] / M);
    }
}

extern "C" void kernel_launch(void* const* d_in, const int* in_sizes, int n_in,
                              void* d_out, int out_size, void* d_ws, size_t ws_size,
                              hipStream_t stream) {
    const float* logits = (const float*)d_in[0];
    const float* pboxes = (const float*)d_in[1];
    const int* glabels = (const int*)d_in[2];
    const float* gboxes = (const float*)d_in[3];
    float* out = (float*)d_out;

    char* ws = (char*)d_ws;
    __half* cost = (__half*)(ws + COST_OFF);
    float* lse = (float*)(ws + LSE_OFF);
    int* vidx = (int*)(ws + VIDX_OFF);
    int* nval = (int*)(ws + NV_OFF);
    int* mq = (int*)(ws + MQ_OFF);
    double* acc = (double*)(ws + ACC_OFF);

    hipMemsetAsync(acc, 0, 4 * sizeof(double), stream);
    compact_kernel<<<BB, 64, 0, stream>>>(glabels, vidx, nval);
    lse_kernel<<<1024, 256, 0, stream>>>(logits, lse, acc);
    cost_kernel<<<BB, 512, 0, stream>>>(logits, pboxes, gboxes, glabels, lse, vidx, nval, cost);
    lsa_kernel<<<BB, 64, 0, stream>>>(cost, nval, mq);
    matched_kernel<<<(BB * GG + 255) / 256, 256, 0, stream>>>(logits, pboxes, gboxes, glabels, lse,
                                                              vidx, nval, mq, acc);
    final_kernel<<<1, 64, 0, stream>>>(nval, acc, out);
}

// Round 6
// 305.682 us; speedup vs baseline: 2.5429x; 1.0084x over previous
//
#include <hip/hip_runtime.h>
#include <hip/hip_fp16.h>
#include <math.h>

#define BB 128
#define QQ 900
#define GG 80
#define CC 92
#define NCL 91
#define NSLOT 15  // ceil(QQ/64)

// ---------------- ws layout (bytes) ----------------
#define COST_OFF 0            // __half[BB*GG*QQ]  18,432,000
#define LSE_OFF  36864000     // float[BB*QQ]
#define VIDX_OFF 37324800     // int[BB*GG]
#define NV_OFF   37365760     // int[BB]
#define MQ_OFF   37366272     // int[BB*GG]
#define ACC_OFF  37407232     // double[4]  [S_base, ce_adj, l1, giou]

#define LSA_LDS_BYTES (GG * QQ * 2 + 128)  // 144,000 + pad for slot-14 overread

// Grid-stride: one wave per (b,q) row. Computes lse AND accumulates the
// no-object CE base sum  sum(lse - logit[91]).
__global__ void lse_kernel(const float* __restrict__ logits, float* __restrict__ lse,
                           double* __restrict__ acc) {
    __shared__ double sd[4];
    int lane = threadIdx.x & 63;
    int wslot = threadIdx.x >> 6;
    int gwave = (blockIdx.x * blockDim.x + threadIdx.x) >> 6;
    int nwaves = (gridDim.x * blockDim.x) >> 6;
    double local = 0.0;
    for (int wid = gwave; wid < BB * QQ; wid += nwaves) {
        const float* row = logits + (size_t)wid * CC;
        float e0 = row[lane];
        float e1 = (lane < CC - 64) ? row[lane + 64] : -INFINITY;
        float mx = fmaxf(e0, e1);
#pragma unroll
        for (int off = 32; off; off >>= 1) mx = fmaxf(mx, __shfl_down(mx, off));
        mx = __shfl(mx, 0);
        float s = expf(e0 - mx) + ((lane < CC - 64) ? expf(e1 - mx) : 0.f);
#pragma unroll
        for (int off = 32; off; off >>= 1) s += __shfl_down(s, off);
        s = __shfl(s, 0);
        float l = mx + logf(s);
        float no = __shfl(e1, NCL - 64);  // lane 27 holds row[91]
        if (lane == 0) {
            lse[wid] = l;
            local += (double)l - (double)no;
        }
    }
    if (lane == 0) sd[wslot] = local;
    __syncthreads();
    if (threadIdx.x == 0) {
        double t = 0.0;
        for (int w = 0; w < 4; ++w) t += sd[w];
        atomicAdd(&acc[0], t);
    }
}

// One block per batch. Wave 0 first does ballot compaction of valid gts
// (fused former compact_kernel; results kept in LDS + written to global for
// the downstream kernels), then all 512 threads build the fp16 cost matrix.
__global__ __launch_bounds__(512) void cost_kernel(const float* __restrict__ logits,
                                                   const float* __restrict__ pboxes,
                                                   const float* __restrict__ gboxes,
                                                   const int* __restrict__ glabels,
                                                   const float* __restrict__ lse,
                                                   int* __restrict__ valid_idx,
                                                   int* __restrict__ nvalid,
                                                   __half* __restrict__ cost) {
    __shared__ int svidx[GG];
    __shared__ int s_n;
    __shared__ int slab[GG];
    __shared__ float sgx0[GG], sgy0[GG], sgx1[GG], sgy1[GG], sgar[GG];
    __shared__ float sgcx[GG], sgcy[GG], sgcz[GG], sgcw[GG];
    int b = blockIdx.x;
    if (threadIdx.x < 64) {
        int lane = threadIdx.x;
        bool v0 = glabels[b * GG + lane] < NCL;
        bool v1 = (lane < GG - 64) ? (glabels[b * GG + 64 + lane] < NCL) : false;
        unsigned long long m0 = __ballot(v0);
        unsigned long long m1 = __ballot(v1);
        int c0 = __popcll(m0);
        unsigned long long lower = lane ? (~0ULL >> (64 - lane)) : 0ULL;
        if (v0) { int p = __popcll(m0 & lower); svidx[p] = lane; valid_idx[b * GG + p] = lane; }
        if (v1) { int p = c0 + __popcll(m1 & lower); svidx[p] = 64 + lane; valid_idx[b * GG + p] = 64 + lane; }
        if (lane == 0) { s_n = c0 + __popcll(m1); nvalid[b] = s_n; }
    }
    __syncthreads();
    int n = s_n;
    for (int k = threadIdx.x; k < n; k += 512) {
        int g = svidx[k];
        slab[k] = glabels[b * GG + g];
        float4 gb = ((const float4*)gboxes)[b * GG + g];
        sgcx[k] = gb.x; sgcy[k] = gb.y; sgcz[k] = gb.z; sgcw[k] = gb.w;
        float gx0 = gb.x - 0.5f * gb.z, gy0 = gb.y - 0.5f * gb.w;
        float gx1 = gb.x + 0.5f * gb.z, gy1 = gb.y + 0.5f * gb.w;
        sgx0[k] = gx0; sgy0[k] = gy0; sgx1[k] = gx1; sgy1[k] = gy1;
        sgar[k] = (gx1 - gx0) * (gy1 - gy0);
    }
    __syncthreads();
    for (int q = threadIdx.x; q < QQ; q += 512) {
        float4 pb = ((const float4*)pboxes)[b * QQ + q];
        float px0 = pb.x - 0.5f * pb.z, py0 = pb.y - 0.5f * pb.w;
        float px1 = pb.x + 0.5f * pb.z, py1 = pb.y + 0.5f * pb.w;
        float parea = (px1 - px0) * (py1 - py0);
        float lse_q = lse[b * QQ + q];
        const float* lrow = logits + ((size_t)(b * QQ) + q) * CC;
        for (int k = 0; k < n; ++k) {
            float l1 = fabsf(pb.x - sgcx[k]) + fabsf(pb.y - sgcy[k]) +
                       fabsf(pb.z - sgcz[k]) + fabsf(pb.w - sgcw[k]);
            float ltx = fmaxf(px0, sgx0[k]), lty = fmaxf(py0, sgy0[k]);
            float rbx = fminf(px1, sgx1[k]), rby = fminf(py1, sgy1[k]);
            float iw = fmaxf(rbx - ltx, 0.f), ih = fmaxf(rby - lty, 0.f);
            float inter = iw * ih;
            float uni = parea + sgar[k] - inter;
            float iou = inter / uni;
            float cx0 = fminf(px0, sgx0[k]), cy0 = fminf(py0, sgy0[k]);
            float cx1 = fmaxf(px1, sgx1[k]), cy1 = fmaxf(py1, sgy1[k]);
            float cw = fmaxf(cx1 - cx0, 0.f), ch = fmaxf(cy1 - cy0, 0.f);
            float ac = cw * ch;
            float giou = iou - (ac - uni) / ac;
            float cls = lse_q - lrow[slab[k]];
            cost[((size_t)(b * GG + k)) * QQ + q] = __float2half_rn(5.f * l1 + cls - 2.f * giou);
        }
    }
}

// Wave64 min-reduce via DPP (row_shr 1/2/4/8 + bcast15/31), result in lane 63.
__device__ __forceinline__ unsigned wave_min_u32(unsigned x) {
    unsigned t;
    t = (unsigned)__builtin_amdgcn_update_dpp((int)x, (int)x, 0x111, 0xF, 0xF, false); x = x < t ? x : t;
    t = (unsigned)__builtin_amdgcn_update_dpp((int)x, (int)x, 0x112, 0xF, 0xF, false); x = x < t ? x : t;
    t = (unsigned)__builtin_amdgcn_update_dpp((int)x, (int)x, 0x114, 0xF, 0xF, false); x = x < t ? x : t;
    t = (unsigned)__builtin_amdgcn_update_dpp((int)x, (int)x, 0x118, 0xF, 0xF, false); x = x < t ? x : t;
    t = (unsigned)__builtin_amdgcn_update_dpp((int)x, (int)x, 0x142, 0xF, 0xF, false); x = x < t ? x : t;
    t = (unsigned)__builtin_amdgcn_update_dpp((int)x, (int)x, 0x143, 0xF, 0xF, false); x = x < t ? x : t;
    return (unsigned)__builtin_amdgcn_readlane((int)x, 63);
}
// fp32 variant (values never NaN here; fminf DPP tree, broadcast lane 63).
__device__ __forceinline__ float wave_min_f32(float x) {
    float t;
#define MSTEP(ctrl)                                                                               \
    t = __uint_as_float((unsigned)__builtin_amdgcn_update_dpp(                                    \
        (int)__float_as_uint(x), (int)__float_as_uint(x), ctrl, 0xF, 0xF, false));                \
    x = fminf(x, t);
    MSTEP(0x111) MSTEP(0x112) MSTEP(0x114) MSTEP(0x118) MSTEP(0x142) MSTEP(0x143)
#undef MSTEP
    return __uint_as_float((unsigned)__builtin_amdgcn_readlane((int)__float_as_uint(x), 63));
}

// Rectangular LSA (scipy SAP semantics), one wave per batch. The batch's full
// fp16 cost matrix (144 KB) is staged into dynamic LDS by 4 waves (waves 1-3
// exit after staging); per-pop cost reads are then ~130-cyc ds_read_u16
// (stride-1: 2 lanes/bank = conflict-free) instead of 200-600-cyc global.
// All LSA state in registers; cross-lane via readlane/DPP.
__global__ __launch_bounds__(256, 1) void lsa_kernel(const __half* __restrict__ cost,
                                                     const int* __restrict__ nvalid,
                                                     int* __restrict__ match_q) {
    extern __shared__ char smem[];
    __half* scost = (__half*)smem;
    int b = blockIdx.x;
    int n = nvalid[b];
    const __half* cbase = cost + (size_t)b * GG * QQ;

    // Stage n rows (ceil to 16B granules; overread stays inside the batch's
    // 144-KB global region and the padded LDS allocation).
    int nv4 = (n * (QQ * 2) + 15) >> 4;
    for (int idx = threadIdx.x; idx < nv4; idx += 256)
        ((uint4*)smem)[idx] = ((const uint4*)cbase)[idx];
    __syncthreads();
    if (threadIdx.x >= 64) return;

    int lane = threadIdx.x;
    float v[NSLOT], sh[NSLOT];
    int path_r[NSLOT], r4c_r[NSLOT];
    float u_r[2], srv_r[2];
    int c4r_r[2];
    unsigned valid_mask = 0x3FFFu | ((lane < QQ - 14 * 64) ? 0x4000u : 0u);

#pragma unroll
    for (int s = 0; s < NSLOT; ++s) { v[s] = 0.f; r4c_r[s] = -1; }
#pragma unroll
    for (int s = 0; s < 2; ++s) { u_r[s] = 0.f; c4r_r[s] = -1; srv_r[s] = 0.f; }

    for (int cur = 0; cur < n; ++cur) {
        unsigned sc = 0, srm = 0;
#pragma unroll
        for (int s = 0; s < NSLOT; ++s) sh[s] = INFINITY;

        int i2 = cur;
        float minv = 0.f;
        int sink = -1;
        for (int pop = 0; pop < 2 * GG && sink < 0; ++pop) {
            // ui = u[i2] (uniform): select slot then readlane
            float uv = (i2 >> 6) ? u_r[1] : u_r[0];
            float ui = __uint_as_float(
                (unsigned)__builtin_amdgcn_readlane((int)__float_as_uint(uv), i2 & 63));
            const __half* lrow = scost + i2 * QQ;
            float cv[NSLOT];
#pragma unroll
            for (int s = 0; s < NSLOT; ++s) cv[s] = __half2float(lrow[s * 64 + lane]);
            float base = minv - ui;
            unsigned act = valid_mask & ~sc;
            float lmin = INFINITY;
            int lslot = 0;
#pragma unroll
            for (int s = 0; s < NSLOT; ++s) {
                if ((act >> s) & 1u) {
                    float r = base + cv[s] - v[s];
                    if (r < sh[s]) { sh[s] = r; path_r[s] = i2; }
                    if (sh[s] < lmin) { lmin = sh[s]; lslot = s; }  // strict < keeps lowest s
                }
            }
            float gmin = wave_min_f32(lmin);
            unsigned cand = (lmin == gmin) ? (unsigned)(lslot * 64 + lane) : 0xFFFFFFFFu;
            int lj = (int)wave_min_u32(cand);  // lowest column among ties
            minv = gmin;
            if (lane == (lj & 63)) sc |= (1u << (lj >> 6));
            // r4c = row4col[lj]
            int rslot = lj >> 6, rlane = lj & 63;
            int rv = -1;
#pragma unroll
            for (int s = 0; s < NSLOT; ++s)
                if (s == rslot) rv = r4c_r[s];
            int r4c = __builtin_amdgcn_readlane(rv, rlane);
            if (r4c == -1) {
                sink = lj;
            } else {
                i2 = r4c;
                if (lane == (i2 & 63)) {
#pragma unroll
                    for (int s = 0; s < 2; ++s)
                        if (s == (i2 >> 6)) { srm |= (1u << s); srv_r[s] = minv; }
                }
            }
        }
        if (sink < 0) break;  // safety (cannot happen: pops/phase <= cur+1 <= 80)
        // dual updates (reference order: before augmentation)
        if (lane == (cur & 63)) {
#pragma unroll
            for (int s = 0; s < 2; ++s)
                if (s == (cur >> 6)) u_r[s] += minv;
        }
#pragma unroll
        for (int s = 0; s < 2; ++s)
            if ((srm >> s) & 1u) u_r[s] += minv - srv_r[s];
#pragma unroll
        for (int s = 0; s < NSLOT; ++s)
            if ((sc >> s) & 1u) v[s] -= (minv - sh[s]);
        // augment (wave-cooperative, uniform walk)
        int j = sink;
        while (true) {
            int pslot = j >> 6, plane = j & 63;
            int pv = 0;
#pragma unroll
            for (int s = 0; s < NSLOT; ++s)
                if (s == pslot) pv = path_r[s];
            int pi = __builtin_amdgcn_readlane(pv, plane);
            if (lane == plane) {
#pragma unroll
                for (int s = 0; s < NSLOT; ++s)
                    if (s == pslot) r4c_r[s] = pi;
            }
            int cslot = pi >> 6, clane = pi & 63;
            int cvv = 0;
#pragma unroll
            for (int s = 0; s < 2; ++s)
                if (s == cslot) cvv = c4r_r[s];
            int nj = __builtin_amdgcn_readlane(cvv, clane);
            if (lane == clane) {
#pragma unroll
                for (int s = 0; s < 2; ++s)
                    if (s == cslot) c4r_r[s] = j;
            }
            j = nj;
            if (pi == cur) break;
        }
    }
#pragma unroll
    for (int s = 0; s < 2; ++s) {
        int r = s * 64 + lane;
        if (r < n) match_q[b * GG + r] = c4r_r[s];
    }
}

// Per matched pair: CE adjustment, L1 sum, (1 - giou) sum.
// Wave-level shfl reduction, one fp64 atomic triple per wave.
__global__ void matched_kernel(const float* __restrict__ logits, const float* __restrict__ pboxes,
                               const float* __restrict__ gboxes, const int* __restrict__ glabels,
                               const float* __restrict__ lse, const int* __restrict__ valid_idx,
                               const int* __restrict__ nvalid, const int* __restrict__ match_q,
                               double* __restrict__ acc) {
    int t = blockIdx.x * blockDim.x + threadIdx.x;
    int lane = threadIdx.x & 63;
    bool ok = t < BB * GG;
    int b = ok ? t / GG : 0;
    int k = ok ? t % GG : 0;
    ok = ok && (k < nvalid[b]);
    int g = ok ? valid_idx[b * GG + k] : 0;
    int q = ok ? match_q[b * GG + k] : 0;
    if (q < 0 || q >= QQ) { ok = false; q = 0; }
    int label = ok ? glabels[b * GG + g] : 0;
    if (label < 0 || label >= CC) label = 0;

    size_t ro = ((size_t)b * QQ + q) * CC;
    float ls = lse[b * QQ + q];
    float nll_lab = ls - logits[ro + label];
    float nll_no = ls - logits[ro + NCL];
    double ce_adj = 0.1 * (double)nll_lab - (double)nll_no;

    float4 pb = ((const float4*)pboxes)[b * QQ + q];
    float4 gb = ((const float4*)gboxes)[b * GG + g];
    float l1 = fabsf(pb.x - gb.x) + fabsf(pb.y - gb.y) + fabsf(pb.z - gb.z) + fabsf(pb.w - gb.w);

    float px0 = pb.x - 0.5f * pb.z, py0 = pb.y - 0.5f * pb.w;
    float px1 = pb.x + 0.5f * pb.z, py1 = pb.y + 0.5f * pb.w;
    float gx0 = gb.x - 0.5f * gb.z, gy0 = gb.y - 0.5f * gb.w;
    float gx1 = gb.x + 0.5f * gb.z, gy1 = gb.y + 0.5f * gb.w;
    float parea = (px1 - px0) * (py1 - py0);
    float garea = (gx1 - gx0) * (gy1 - gy0);
    float ltx = fmaxf(px0, gx0), lty = fmaxf(py0, gy0);
    float rbx = fminf(px1, gx1), rby = fminf(py1, gy1);
    float iw = fmaxf(rbx - ltx, 0.f), ih = fmaxf(rby - lty, 0.f);
    float inter = iw * ih;
    float uni = parea + garea - inter;
    float iou = inter / uni;
    float cx0 = fminf(px0, gx0), cy0 = fminf(py0, gy0);
    float cx1 = fmaxf(px1, gx1), cy1 = fmaxf(py1, gy1);
    float cw = fmaxf(cx1 - cx0, 0.f), ch = fmaxf(cy1 - cy0, 0.f);
    float ac = cw * ch;
    float giou = iou - (ac - uni) / ac;

    double ce = ok ? ce_adj : 0.0;
    double dl1 = ok ? (double)l1 : 0.0;
    double dgi = ok ? (1.0 - (double)giou) : 0.0;
#pragma unroll
    for (int off = 32; off; off >>= 1) {
        ce += __shfl_down(ce, off);
        dl1 += __shfl_down(dl1, off);
        dgi += __shfl_down(dgi, off);
    }
    if (lane == 0) {
        atomicAdd(&acc[1], ce);
        atomicAdd(&acc[2], dl1);
        atomicAdd(&acc[3], dgi);
    }
}

// One wave: reduce nvalid -> M, compute the three losses.
__global__ __launch_bounds__(64) void final_kernel(const int* __restrict__ nvalid,
                                                   const double* __restrict__ acc,
                                                   float* __restrict__ out) {
    int lane = threadIdx.x;
    int m = nvalid[lane] + nvalid[64 + lane];  // BB = 128
#pragma unroll
    for (int off = 32; off; off >>= 1) m += __shfl_down(m, off);
    if (lane == 0) {
        double M = (double)m;
        double sum_w = (double)(BB * QQ) - 0.9 * M;
        out[0] = (float)((acc[0] + acc[1]) / sum_w);
        out[1] = (float)(acc[2] / (4.0 * M));
        out[2] = (float)(acc[3] / M);
    }
}

extern "C" void kernel_launch(void* const* d_in, const int* in_sizes, int n_in,
                              void* d_out, int out_size, void* d_ws, size_t ws_size,
                              hipStream_t stream) {
    const float* logits = (const float*)d_in[0];
    const float* pboxes = (const float*)d_in[1];
    const int* glabels = (const int*)d_in[2];
    const float* gboxes = (const float*)d_in[3];
    float* out = (float*)d_out;

    char* ws = (char*)d_ws;
    __half* cost = (__half*)(ws + COST_OFF);
    float* lse = (float*)(ws + LSE_OFF);
    int* vidx = (int*)(ws + VIDX_OFF);
    int* nval = (int*)(ws + NV_OFF);
    int* mq = (int*)(ws + MQ_OFF);
    double* acc = (double*)(ws + ACC_OFF);

    // Opt in to >64 KB dynamic LDS (idempotent; harmless if a no-op on AMD).
    (void)hipFuncSetAttribute((const void*)lsa_kernel,
                              hipFuncAttributeMaxDynamicSharedMemorySize, LSA_LDS_BYTES);

    hipMemsetAsync(acc, 0, 4 * sizeof(double), stream);
    lse_kernel<<<1024, 256, 0, stream>>>(logits, lse, acc);
    cost_kernel<<<BB, 512, 0, stream>>>(logits, pboxes, gboxes, glabels, lse, vidx, nval, cost);
    lsa_kernel<<<BB, 256, LSA_LDS_BYTES, stream>>>(cost, nval, mq);
    matched_kernel<<<(BB * GG + 255) / 256, 256, 0, stream>>>(logits, pboxes, gboxes, glabels, lse,
                                                              vidx, nval, mq, acc);
    final_kernel<<<1, 64, 0, stream>>>(nval, acc, out);
}

// Round 10
// 292.031 us; speedup vs baseline: 2.6618x; 1.0467x over previous
//
#include <hip/hip_runtime.h>
#include <math.h>

#define BB 128
#define QQ 900
#define GG 80
#define CC 92
#define NCL 91
#define NSLOT 15  // ceil(QQ/64)

// ---------------- ws layout (bytes) ----------------
#define COST_OFF 0            // float[BB*GG*QQ]  36,864,000
#define LSE_OFF  36864000     // float[BB*QQ]
#define VIDX_OFF 37324800     // int[BB*GG]
#define NV_OFF   37365760     // int[BB]
#define ACC_OFF  37407232     // double[4]  [S_base, ce_adj, l1, giou]

// Fused front kernel: one block per batch.
//  wave 0: ballot-compaction of valid gts -> valid_idx/nvalid
//  all:    per-q lse (fp32) -> LDS + global; no-object CE base sum
//  all:    fp32 cost matrix cost[b][k][q] = 5*L1 + class - 2*giou
__global__ __launch_bounds__(512) void front_kernel(const float* __restrict__ logits,
                                                    const float* __restrict__ pboxes,
                                                    const float* __restrict__ gboxes,
                                                    const int* __restrict__ glabels,
                                                    float* __restrict__ lse_g,
                                                    int* __restrict__ valid_idx,
                                                    int* __restrict__ nvalid,
                                                    float* __restrict__ cost,
                                                    double* __restrict__ acc) {
    __shared__ int svidx[GG];
    __shared__ int s_n;
    __shared__ int slab[GG];
    __shared__ float sgx0[GG], sgy0[GG], sgx1[GG], sgy1[GG], sgar[GG];
    __shared__ float sgcx[GG], sgcy[GG], sgcz[GG], sgcw[GG];
    __shared__ float slse[QQ];
    __shared__ double sce[8];
    int b = blockIdx.x;
    if (threadIdx.x < 64) {
        int lane = threadIdx.x;
        bool v0 = glabels[b * GG + lane] < NCL;
        bool v1 = (lane < GG - 64) ? (glabels[b * GG + 64 + lane] < NCL) : false;
        unsigned long long m0 = __ballot(v0);
        unsigned long long m1 = __ballot(v1);
        int c0 = __popcll(m0);
        unsigned long long lower = lane ? (~0ULL >> (64 - lane)) : 0ULL;
        if (v0) { int p = __popcll(m0 & lower); svidx[p] = lane; valid_idx[b * GG + p] = lane; }
        if (v1) { int p = c0 + __popcll(m1 & lower); svidx[p] = 64 + lane; valid_idx[b * GG + p] = 64 + lane; }
        if (lane == 0) { s_n = c0 + __popcll(m1); nvalid[b] = s_n; }
    }
    __syncthreads();
    int n = s_n;

    // lse pass (92 floats = exactly 23 float4 per row)
    double local = 0.0;
    for (int q = threadIdx.x; q < QQ; q += 512) {
        const float4* row4 = (const float4*)(logits + ((size_t)(b * QQ) + q) * CC);
        float mx = -INFINITY;
        for (int c = 0; c < 23; ++c) {
            float4 x = row4[c];
            mx = fmaxf(mx, fmaxf(fmaxf(x.x, x.y), fmaxf(x.z, x.w)));
        }
        float ssum = 0.f;
        float e91 = 0.f;
        for (int c = 0; c < 23; ++c) {
            float4 x = row4[c];
            ssum += expf(x.x - mx) + expf(x.y - mx) + expf(x.z - mx) + expf(x.w - mx);
            if (c == 22) e91 = x.w;  // element 91
        }
        float l = mx + logf(ssum);
        slse[q] = l;
        lse_g[b * QQ + q] = l;
        local += (double)l - (double)e91;
    }
#pragma unroll
    for (int off = 32; off; off >>= 1) local += __shfl_down(local, off);
    if ((threadIdx.x & 63) == 0) sce[threadIdx.x >> 6] = local;

    // gt staging
    for (int k = threadIdx.x; k < n; k += 512) {
        int g = svidx[k];
        slab[k] = glabels[b * GG + g];
        float4 gb = ((const float4*)gboxes)[b * GG + g];
        sgcx[k] = gb.x; sgcy[k] = gb.y; sgcz[k] = gb.z; sgcw[k] = gb.w;
        float gx0 = gb.x - 0.5f * gb.z, gy0 = gb.y - 0.5f * gb.w;
        float gx1 = gb.x + 0.5f * gb.z, gy1 = gb.y + 0.5f * gb.w;
        sgx0[k] = gx0; sgy0[k] = gy0; sgx1[k] = gx1; sgy1[k] = gy1;
        sgar[k] = (gx1 - gx0) * (gy1 - gy0);
    }
    __syncthreads();
    if (threadIdx.x == 0) {
        double t = 0.0;
        for (int w = 0; w < 8; ++w) t += sce[w];
        atomicAdd(&acc[0], t);
    }
    // cost matrix
    for (int q = threadIdx.x; q < QQ; q += 512) {
        float4 pb = ((const float4*)pboxes)[b * QQ + q];
        float px0 = pb.x - 0.5f * pb.z, py0 = pb.y - 0.5f * pb.w;
        float px1 = pb.x + 0.5f * pb.z, py1 = pb.y + 0.5f * pb.w;
        float parea = (px1 - px0) * (py1 - py0);
        float lse_q = slse[q];
        const float* lrow = logits + ((size_t)(b * QQ) + q) * CC;
        for (int k = 0; k < n; ++k) {
            float l1 = fabsf(pb.x - sgcx[k]) + fabsf(pb.y - sgcy[k]) +
                       fabsf(pb.z - sgcz[k]) + fabsf(pb.w - sgcw[k]);
            float ltx = fmaxf(px0, sgx0[k]), lty = fmaxf(py0, sgy0[k]);
            float rbx = fminf(px1, sgx1[k]), rby = fminf(py1, sgy1[k]);
            float iw = fmaxf(rbx - ltx, 0.f), ih = fmaxf(rby - lty, 0.f);
            float inter = iw * ih;
            float uni = parea + sgar[k] - inter;
            float iou = inter / uni;
            float cx0 = fminf(px0, sgx0[k]), cy0 = fminf(py0, sgy0[k]);
            float cx1 = fmaxf(px1, sgx1[k]), cy1 = fmaxf(py1, sgy1[k]);
            float cw = fmaxf(cx1 - cx0, 0.f), ch = fmaxf(cy1 - cy0, 0.f);
            float ac = cw * ch;
            float giou = iou - (ac - uni) / ac;
            float cls = lse_q - lrow[slab[k]];
            cost[((size_t)(b * GG + k)) * QQ + q] = 5.f * l1 + cls - 2.f * giou;
        }
    }
}

// Wave64 min-reduce via DPP (row_shr 1/2/4/8 + bcast15/31), result in lane 63.
__device__ __forceinline__ unsigned wave_min_u32(unsigned x) {
    unsigned t;
    t = (unsigned)__builtin_amdgcn_update_dpp((int)x, (int)x, 0x111, 0xF, 0xF, false); x = x < t ? x : t;
    t = (unsigned)__builtin_amdgcn_update_dpp((int)x, (int)x, 0x112, 0xF, 0xF, false); x = x < t ? x : t;
    t = (unsigned)__builtin_amdgcn_update_dpp((int)x, (int)x, 0x114, 0xF, 0xF, false); x = x < t ? x : t;
    t = (unsigned)__builtin_amdgcn_update_dpp((int)x, (int)x, 0x118, 0xF, 0xF, false); x = x < t ? x : t;
    t = (unsigned)__builtin_amdgcn_update_dpp((int)x, (int)x, 0x142, 0xF, 0xF, false); x = x < t ? x : t;
    t = (unsigned)__builtin_amdgcn_update_dpp((int)x, (int)x, 0x143, 0xF, 0xF, false); x = x < t ? x : t;
    return (unsigned)__builtin_amdgcn_readlane((int)x, 63);
}
// fp32 variant (fminf; values here are never NaN).
__device__ __forceinline__ float wave_min_f32(float x) {
    float t;
#define MSTEP(ctrl)                                                                               \
    t = __uint_as_float((unsigned)__builtin_amdgcn_update_dpp(                                    \
        (int)__float_as_uint(x), (int)__float_as_uint(x), ctrl, 0xF, 0xF, false));                \
    x = fminf(x, t);
    MSTEP(0x111) MSTEP(0x112) MSTEP(0x114) MSTEP(0x118) MSTEP(0x142) MSTEP(0x143)
#undef MSTEP
    return __uint_as_float((unsigned)__builtin_amdgcn_readlane((int)__float_as_uint(x), 63));
}

// One exact SAP phase (scipy semantics) for row `cur`.
// Bit-for-bit the R3/R6-proven dataflow; global fp32 cost rows.
__device__ __forceinline__ bool sap_phase(int cur, int lane, const float* cbase,
                                          unsigned valid_mask, float (&v)[NSLOT],
                                          int (&r4c_r)[NSLOT], float (&u_r)[2],
                                          int (&c4r_r)[2]) {
    float sh[NSLOT];
    int path_r[NSLOT];
    float srv_r[2] = {0.f, 0.f};
    unsigned sc = 0, srm = 0;
#pragma unroll
    for (int s = 0; s < NSLOT; ++s) sh[s] = INFINITY;
    int i2 = cur;
    float minv = 0.f;
    int sink = -1;
    for (int pop = 0; pop < QQ && sink < 0; ++pop) {
        float uv = (i2 >> 6) ? u_r[1] : u_r[0];
        float ui = __uint_as_float(
            (unsigned)__builtin_amdgcn_readlane((int)__float_as_uint(uv), i2 & 63));
        const float* crow = cbase + (size_t)i2 * QQ;
        float cv[NSLOT];
#pragma unroll
        for (int s = 0; s < NSLOT; ++s) {
            int j = s * 64 + lane;
            cv[s] = (j < QQ) ? crow[j] : 0.f;
        }
        float base = minv - ui;
        unsigned act = valid_mask & ~sc;
        float lmin = INFINITY;
        int lslot = 0;
#pragma unroll
        for (int s = 0; s < NSLOT; ++s) {
            if ((act >> s) & 1u) {
                float r = base + cv[s] - v[s];
                if (r < sh[s]) { sh[s] = r; path_r[s] = i2; }
                if (sh[s] < lmin) { lmin = sh[s]; lslot = s; }
            }
        }
        float gmin = wave_min_f32(lmin);
        unsigned cand = (lmin == gmin) ? (unsigned)(lslot * 64 + lane) : 0xFFFFFFFFu;
        int lj = (int)wave_min_u32(cand);  // lowest column among ties
        minv = gmin;
        if (lane == (lj & 63)) sc |= (1u << (lj >> 6));
        int rv = -1;
#pragma unroll
        for (int s = 0; s < NSLOT; ++s)
            if (s == (lj >> 6)) rv = r4c_r[s];
        int r4c = __builtin_amdgcn_readlane(rv, lj & 63);
        if (r4c == -1) {
            sink = lj;
        } else {
            i2 = r4c;
            if (lane == (i2 & 63)) {
#pragma unroll
                for (int s = 0; s < 2; ++s)
                    if (s == (i2 >> 6)) { srm |= (1u << s); srv_r[s] = minv; }
            }
        }
    }
    if (sink < 0) return false;
    // dual updates (reference order: before augmentation)
    if (lane == (cur & 63)) {
#pragma unroll
        for (int s = 0; s < 2; ++s)
            if (s == (cur >> 6)) u_r[s] += minv;
    }
#pragma unroll
    for (int s = 0; s < 2; ++s)
        if ((srm >> s) & 1u) u_r[s] += minv - srv_r[s];
#pragma unroll
    for (int s = 0; s < NSLOT; ++s)
        if ((sc >> s) & 1u) v[s] -= (minv - sh[s]);
    // augment (wave-cooperative, uniform walk)
    int j = sink;
    while (true) {
        int pslot = j >> 6, plane = j & 63;
        int pv = 0;
#pragma unroll
        for (int s = 0; s < NSLOT; ++s)
            if (s == pslot) pv = path_r[s];
        int pi = __builtin_amdgcn_readlane(pv, plane);
        if (lane == plane) {
#pragma unroll
            for (int s = 0; s < NSLOT; ++s)
                if (s == pslot) r4c_r[s] = pi;
        }
        int cslot = pi >> 6, clane = pi & 63;
        int cvv = 0;
#pragma unroll
        for (int s = 0; s < 2; ++s)
            if (s == cslot) cvv = c4r_r[s];
        int nj = __builtin_amdgcn_readlane(cvv, clane);
        if (lane == clane) {
#pragma unroll
            for (int s = 0; s < 2; ++s)
                if (s == cslot) c4r_r[s] = j;
        }
        j = nj;
        if (pi == cur) break;
    }
    return true;
}

// BISECTION ROUND: R9 minus colmin. v = 0 init, sequential SAP rows 0..n-1 --
// exactly the R3/R6-proven algorithm -- inside the R7-R9 fused frame
// (front_kernel + fused matched tail). If this passes, colmin-init was the
// bug shared by R7/R8/R9; if it fails at 0.2656, the fused frame is guilty.
// One 64-lane wave per batch; all state in registers.
__global__ __launch_bounds__(64, 1) void lsa_kernel(const float* __restrict__ cost,
                                                    const int* __restrict__ nvalid,
                                                    const int* __restrict__ valid_idx,
                                                    const int* __restrict__ glabels,
                                                    const float* __restrict__ lse_g,
                                                    const float* __restrict__ pboxes,
                                                    const float* __restrict__ gboxes,
                                                    const float* __restrict__ logits,
                                                    double* __restrict__ acc) {
    int b = blockIdx.x;
    int n = nvalid[b];
    const float* cbase = cost + (size_t)b * GG * QQ;
    int lane = threadIdx.x;

    float v[NSLOT];
    int r4c_r[NSLOT];
    float u_r[2];
    int c4r_r[2];
    unsigned valid_mask = 0x3FFFu | ((lane < QQ - 14 * 64) ? 0x4000u : 0u);
#pragma unroll
    for (int s = 0; s < NSLOT; ++s) { v[s] = 0.f; r4c_r[s] = -1; }
#pragma unroll
    for (int s = 0; s < 2; ++s) { u_r[s] = 0.f; c4r_r[s] = -1; }

    // sequential SAP phases, rows 0..n-1 (scipy order; R3/R6-proven)
    for (int cur = 0; cur < n; ++cur)
        sap_phase(cur, lane, cbase, valid_mask, v, r4c_r, u_r, c4r_r);

    // ---- fused matched-pair losses ----
    double ce = 0.0, dl1 = 0.0, dgi = 0.0;
#pragma unroll
    for (int s = 0; s < 2; ++s) {
        int r = s * 64 + lane;
        int q = c4r_r[s];
        if (r < n && q >= 0 && q < QQ) {
            int g = valid_idx[b * GG + r];
            int label = glabels[b * GG + g];
            if (label < 0 || label >= CC) label = 0;
            size_t ro = ((size_t)b * QQ + q) * CC;
            float ls = lse_g[b * QQ + q];
            float nll_lab = ls - logits[ro + label];
            float nll_no = ls - logits[ro + NCL];
            ce += 0.1 * (double)nll_lab - (double)nll_no;
            float4 pb = ((const float4*)pboxes)[b * QQ + q];
            float4 gb = ((const float4*)gboxes)[b * GG + g];
            float l1 = fabsf(pb.x - gb.x) + fabsf(pb.y - gb.y) + fabsf(pb.z - gb.z) + fabsf(pb.w - gb.w);
            float px0 = pb.x - 0.5f * pb.z, py0 = pb.y - 0.5f * pb.w;
            float px1 = pb.x + 0.5f * pb.z, py1 = pb.y + 0.5f * pb.w;
            float gx0 = gb.x - 0.5f * gb.z, gy0 = gb.y - 0.5f * gb.w;
            float gx1 = gb.x + 0.5f * gb.z, gy1 = gb.y + 0.5f * gb.w;
            float parea = (px1 - px0) * (py1 - py0);
            float garea = (gx1 - gx0) * (gy1 - gy0);
            float ltx = fmaxf(px0, gx0), lty = fmaxf(py0, gy0);
            float rbx = fminf(px1, gx1), rby = fminf(py1, gy1);
            float iw = fmaxf(rbx - ltx, 0.f), ih = fmaxf(rby - lty, 0.f);
            float inter = iw * ih;
            float uni = parea + garea - inter;
            float iou = inter / uni;
            float cx0 = fminf(px0, gx0), cy0 = fminf(py0, gy0);
            float cx1 = fmaxf(px1, gx1), cy1 = fmaxf(py1, gy1);
            float cw = fmaxf(cx1 - cx0, 0.f), ch = fmaxf(cy1 - cy0, 0.f);
            float ac = cw * ch;
            float giou = iou - (ac - uni) / ac;
            dl1 += (double)l1;
            dgi += 1.0 - (double)giou;
        }
    }
#pragma unroll
    for (int off = 32; off; off >>= 1) {
        ce += __shfl_down(ce, off);
        dl1 += __shfl_down(dl1, off);
        dgi += __shfl_down(dgi, off);
    }
    if (lane == 0) {
        atomicAdd(&acc[1], ce);
        atomicAdd(&acc[2], dl1);
        atomicAdd(&acc[3], dgi);
    }
}

// One wave: reduce nvalid -> M, compute the three losses.
__global__ __launch_bounds__(64) void final_kernel(const int* __restrict__ nvalid,
                                                   const double* __restrict__ acc,
                                                   float* __restrict__ out) {
    int lane = threadIdx.x;
    int m = nvalid[lane] + nvalid[64 + lane];  // BB = 128
#pragma unroll
    for (int off = 32; off; off >>= 1) m += __shfl_down(m, off);
    if (lane == 0) {
        double M = (double)m;
        double sum_w = (double)(BB * QQ) - 0.9 * M;
        out[0] = (float)((acc[0] + acc[1]) / sum_w);
        out[1] = (float)(acc[2] / (4.0 * M));
        out[2] = (float)(acc[3] / M);
    }
}

extern "C" void kernel_launch(void* const* d_in, const int* in_sizes, int n_in,
                              void* d_out, int out_size, void* d_ws, size_t ws_size,
                              hipStream_t stream) {
    const float* logits = (const float*)d_in[0];
    const float* pboxes = (const float*)d_in[1];
    const int* glabels = (const int*)d_in[2];
    const float* gboxes = (const float*)d_in[3];
    float* out = (float*)d_out;

    char* ws = (char*)d_ws;
    float* cost = (float*)(ws + COST_OFF);
    float* lse = (float*)(ws + LSE_OFF);
    int* vidx = (int*)(ws + VIDX_OFF);
    int* nval = (int*)(ws + NV_OFF);
    double* acc = (double*)(ws + ACC_OFF);

    hipMemsetAsync(acc, 0, 4 * sizeof(double), stream);
    front_kernel<<<BB, 512, 0, stream>>>(logits, pboxes, gboxes, glabels, lse, vidx, nval, cost, acc);
    lsa_kernel<<<BB, 64, 0, stream>>>(cost, nval, vidx, glabels, lse, pboxes, gboxes, logits, acc);
    final_kernel<<<1, 64, 0, stream>>>(nval, acc, out);
}